// Round 15
// baseline (343.396 us; speedup 1.0000x reference)
//
#include <hip/hip_runtime.h>
#include <hip/hip_bf16.h>

typedef __attribute__((ext_vector_type(4))) float f32x4;
typedef __attribute__((ext_vector_type(8))) short s16x8;
typedef __attribute__((ext_vector_type(4))) short s16x4;

__device__ __forceinline__ short f2bf(float f) {
  union { float f; unsigned u; } c; c.f = f;
  unsigned r = c.u + 0x7fffu + ((c.u >> 16) & 1u);
  return (short)(r >> 16);
}
__device__ __forceinline__ float bf2f(short h) {
  union { unsigned u; float f; } c; c.u = ((unsigned)(unsigned short)h) << 16;
  return c.f;
}
__device__ __forceinline__ s16x8 cvt8(const f32x4& lo, const f32x4& hi) {
  s16x8 v;
  v[0] = f2bf(lo[0]); v[1] = f2bf(lo[1]); v[2] = f2bf(lo[2]); v[3] = f2bf(lo[3]);
  v[4] = f2bf(hi[0]); v[5] = f2bf(hi[1]); v[6] = f2bf(hi[2]); v[7] = f2bf(hi[3]);
  return v;
}

__device__ __forceinline__ void gl_lds16(const short* g, char* l) {
  __builtin_amdgcn_global_load_lds(
      (const __attribute__((address_space(1))) unsigned int*)g,
      (__attribute__((address_space(3))) unsigned int*)l, 16, 0, 0);
}

// ---------------------------------------------------------------------------
// Runtime parameter pack for one GEMM problem
// ---------------------------------------------------------------------------
struct GemmP {
  const short* A; int hbA; long sAo, sAi; int lda;
  const short* B; int hbB; long sBo, sBi; int ldb;
  void* C; int hbC; long sCo, sCi; int ldc;
  const float* bias; const float* res1; const float* res2;
  int M, N, K; float alpha; int nvalid;
  int biasm;   // bias indexed by M row (transposed-output GEMMs)
};

// ---------------------------------------------------------------------------
// GEMM body (all-bf16 in): C = alpha*A[M,K]@B[N,K]^T (+bias/res/softmax)
// ---------------------------------------------------------------------------
template<int CF32, int BM, int BN, int WRN, int WCN, int RING,
         int SM, int RELU, int NRES>
__device__ __forceinline__
void gemm_body(const GemmP& P, int bx, int by, int bz)
{
  constexpr int WAVES = WRN * WCN;
  constexpr int T = WAVES * 64;
  constexpr int MI = BM / (WRN * 16), NI = BN / (WCN * 16);
  constexpr int ACH = BM * 8 / T, BCH = BN * 8 / T;
  constexpr int L   = ACH + BCH;
  constexpr int ABYTES = BM * 128;
  constexpr int TBYTES = (BM + BN) * 128;
  constexpr int LSTR = BN + (CF32 ? 4 : 8);
  constexpr int EPIB = BM * LSTR * (CF32 ? 4 : 2);
  constexpr int SMEMB = (RING * TBYTES > EPIB) ? RING * TBYTES : EPIB;
  __shared__ __align__(16) char smem[SMEMB];

  const int tid  = threadIdx.x;
  const int lane = tid & 63;
  const int wid  = tid >> 6;
  const int wr   = wid / WCN, wc = wid % WCN;

  const int m0 = bx * BM, n0 = by * BN;
  const int z  = bz;

  const int zA = z / P.hbA, zAi = z - zA * P.hbA;
  const int zB = z / P.hbB, zBi = z - zB * P.hbB;
  const int zC = z / P.hbC, zCi = z - zC * P.hbC;
  const short* Ab = P.A + (long)zA * P.sAo + (long)zAi * P.sAi;
  const short* Bb = P.B + (long)zB * P.sBo + (long)zBi * P.sBi;
  char*        Cb = (char*)P.C + ((long)zC * P.sCo + (long)zCi * P.sCi) * (CF32 ? 4 : 2);

  int aL[ACH]; long aG[ACH];
#pragma unroll
  for (int j = 0; j < ACH; ++j) {
    int chunk = (j * WAVES + wid) * 64 + lane;
    int row = chunk >> 3;
    int c   = (chunk & 7) ^ (row & 7);
    int gr = m0 + row; if (gr > P.M - 1) gr = P.M - 1;
    aL[j] = chunk * 16;
    aG[j] = (long)gr * P.lda + c * 8;
  }
  int bL[BCH]; long bG[BCH];
#pragma unroll
  for (int j = 0; j < BCH; ++j) {
    int chunk = (j * WAVES + wid) * 64 + lane;
    int row = chunk >> 3;
    int c   = (chunk & 7) ^ (row & 7);
    int gc = n0 + row; if (gc > P.N - 1) gc = P.N - 1;
    bL[j] = chunk * 16;
    bG[j] = (long)gc * P.ldb + c * 8;
  }

  auto stage = [&](int buf, int kt) {
    const short* Akt = Ab + (long)kt * 64;
    char* base = smem + buf * TBYTES;
#pragma unroll
    for (int j = 0; j < ACH; ++j) gl_lds16(Akt + aG[j], base + aL[j]);
    const short* Bkt = Bb + (long)kt * 64;
#pragma unroll
    for (int j = 0; j < BCH; ++j) gl_lds16(Bkt + bG[j], base + ABYTES + bL[j]);
  };

  int ard[2][MI], brd[2][NI];
#pragma unroll
  for (int kk = 0; kk < 2; ++kk) {
    int kgr = kk * 4 + (lane >> 4);
#pragma unroll
    for (int mi = 0; mi < MI; ++mi) {
      int m = wr * (BM / WRN) + mi * 16 + (lane & 15);
      ard[kk][mi] = m * 128 + ((kgr ^ (m & 7)) << 4);
    }
#pragma unroll
    for (int ni = 0; ni < NI; ++ni) {
      int n = wc * (BN / WCN) + ni * 16 + (lane & 15);
      brd[kk][ni] = ABYTES + n * 128 + ((kgr ^ (n & 7)) << 4);
    }
  }

  const int NT = P.K >> 6;
#pragma unroll
  for (int p = 0; p < RING; ++p) if (p < NT) stage(p, p);

  f32x4 acc[MI][NI];
#pragma unroll
  for (int mi = 0; mi < MI; ++mi)
#pragma unroll
    for (int ni = 0; ni < NI; ++ni) acc[mi][ni] = (f32x4){0.f, 0.f, 0.f, 0.f};

  int bufi = 0;
  for (int t = 0; t < NT; ++t) {
    const int rem = NT - t;
    if constexpr (RING == 3) {
      if (rem >= 3)      asm volatile("s_waitcnt vmcnt(%0)" :: "n"(2 * L) : "memory");
      else if (rem == 2) asm volatile("s_waitcnt vmcnt(%0)" :: "n"(L) : "memory");
      else               asm volatile("s_waitcnt vmcnt(0)" ::: "memory");
    } else if constexpr (RING == 2) {
      if (rem >= 2)      asm volatile("s_waitcnt vmcnt(%0)" :: "n"(L) : "memory");
      else               asm volatile("s_waitcnt vmcnt(0)" ::: "memory");
    } else {
      asm volatile("s_waitcnt vmcnt(0)" ::: "memory");
    }
    asm volatile("s_barrier" ::: "memory");

    const char* base = smem + bufi * TBYTES;
#pragma unroll
    for (int kk = 0; kk < 2; ++kk) {
      s16x8 af[MI];
#pragma unroll
      for (int mi = 0; mi < MI; ++mi) af[mi] = *(const s16x8*)(base + ard[kk][mi]);
#pragma unroll
      for (int ni = 0; ni < NI; ++ni) {
        s16x8 bf = *(const s16x8*)(base + brd[kk][ni]);
#pragma unroll
        for (int mi = 0; mi < MI; ++mi)
          acc[mi][ni] = __builtin_amdgcn_mfma_f32_16x16x32_bf16(af[mi], bf, acc[mi][ni], 0, 0, 0);
      }
    }

    if (t + RING < NT) {
      asm volatile("s_waitcnt lgkmcnt(0)" ::: "memory");
      asm volatile("s_barrier" ::: "memory");
      stage(bufi, t + RING);
    }
    bufi = (bufi + 1 == RING) ? 0 : bufi + 1;
  }

  if constexpr (SM) {
#pragma unroll
    for (int mi = 0; mi < MI; ++mi) {
#pragma unroll
      for (int j = 0; j < 4; ++j) {
        float mx = -3.0e38f;
#pragma unroll
        for (int ni = 0; ni < NI; ++ni) {
          int col = n0 + wc * (BN / WCN) + ni * 16 + (lane & 15);
          float s = acc[mi][ni][j] * P.alpha;
          acc[mi][ni][j] = (col < P.nvalid) ? s : -3.0e38f;
          mx = fmaxf(mx, acc[mi][ni][j]);
        }
#pragma unroll
        for (int o = 1; o < 16; o <<= 1) mx = fmaxf(mx, __shfl_xor(mx, o));
        float sum = 0.f;
#pragma unroll
        for (int ni = 0; ni < NI; ++ni) {
          int col = n0 + wc * (BN / WCN) + ni * 16 + (lane & 15);
          float e = (col < P.nvalid) ? __expf(acc[mi][ni][j] - mx) : 0.f;
          acc[mi][ni][j] = e;
          sum += e;
        }
#pragma unroll
        for (int o = 1; o < 16; o <<= 1) sum += __shfl_xor(sum, o);
        float inv = 1.f / sum;
#pragma unroll
        for (int ni = 0; ni < NI; ++ni) acc[mi][ni][j] *= inv;
      }
    }
  }
  const float aep = SM ? 1.f : P.alpha;

  asm volatile("s_waitcnt lgkmcnt(0)" ::: "memory");
  __syncthreads();

  {
    float* lf = (float*)smem;
    short* lh = (short*)smem;
#pragma unroll
    for (int mi = 0; mi < MI; ++mi)
#pragma unroll
      for (int ni = 0; ni < NI; ++ni) {
        int c_loc = wc * (BN / WCN) + ni * 16 + (lane & 15);
        float bv = (P.bias && P.biasm == 0) ? P.bias[n0 + c_loc] : 0.f;
        int rb = wr * (BM / WRN) + mi * 16 + ((lane >> 4) << 2);
#pragma unroll
        for (int j = 0; j < 4; ++j) {
          float v = acc[mi][ni][j] * aep + bv;
          if constexpr (CF32) lf[(rb + j) * LSTR + c_loc] = v;
          else                lh[(rb + j) * LSTR + c_loc] = f2bf(v);
        }
      }
  }
  __syncthreads();

  constexpr int CPR = BN / 8;
  constexpr int RP  = T / CPR;
  const int rr0 = tid / CPR;
  const int cc  = (tid % CPR) * 8;
  for (int r = rr0; r < BM; r += RP) {
    const int gr = m0 + r;
    if (gr >= P.M) break;
    f32x4 a, b;
    if constexpr (CF32) {
      a = *(const f32x4*)((const float*)smem + (long)r * LSTR + cc);
      b = *(const f32x4*)((const float*)smem + (long)r * LSTR + cc + 4);
    } else {
      s16x8 h = *(const s16x8*)((const short*)smem + (long)r * LSTR + cc);
#pragma unroll
      for (int j = 0; j < 4; ++j) { a[j] = bf2f(h[j]); b[j] = bf2f(h[j + 4]); }
    }
    if (P.biasm) {
      float bm = P.bias[gr];
#pragma unroll
      for (int j = 0; j < 4; ++j) { a[j] += bm; b[j] += bm; }
    }
    const long gb = (long)gr * P.ldc + n0 + cc;
    if constexpr (NRES >= 1) {
      f32x4 r1 = *(const f32x4*)(P.res1 + gb), r2 = *(const f32x4*)(P.res1 + gb + 4);
#pragma unroll
      for (int j = 0; j < 4; ++j) { a[j] += r1[j]; b[j] += r2[j]; }
    }
    if constexpr (NRES >= 2) {
      f32x4 r1 = *(const f32x4*)(P.res2 + gb), r2 = *(const f32x4*)(P.res2 + gb + 4);
#pragma unroll
      for (int j = 0; j < 4; ++j) { a[j] += r1[j]; b[j] += r2[j]; }
    }
    if constexpr (RELU) {
#pragma unroll
      for (int j = 0; j < 4; ++j) { a[j] = fmaxf(a[j], 0.f); b[j] = fmaxf(b[j], 0.f); }
    }
    if constexpr (CF32) {
      *(f32x4*)((float*)Cb + gb) = a;
      *(f32x4*)((float*)Cb + gb + 4) = b;
    } else {
      *(s16x8*)((short*)Cb + gb) = cvt8(a, b);
    }
  }
}

// XCD-chunked bijective remap over a linear id
__device__ __forceinline__ int xcd_remap(int o, int nwg)
{
  const int q = nwg >> 3, r = nwg & 7;
  const int xcd = o & 7, slot = o >> 3;
  return (xcd < r ? xcd * (q + 1) : r * (q + 1) + (xcd - r) * q) + slot;
}

// ---------------------------------------------------------------------------
// Single-problem GEMM kernel
// ---------------------------------------------------------------------------
template<int CF32, int BM, int BN, int WRN, int WCN, int RING,
         int SM, int RELU, int NRES, int SWZ>
__global__ __launch_bounds__(WRN * WCN * 64, 2)
void gemm_k(GemmP P)
{
  int bx = blockIdx.x, by = blockIdx.y, bz = blockIdx.z;
  if constexpr (SWZ == 1) {
    const int gx = gridDim.x, gy = gridDim.y;
    const int w = xcd_remap(by * gx + bx, gx * gy);
    bx = w / gy; by = w - bx * gy;
  } else if constexpr (SWZ == 2) {
    const int gx = gridDim.x, gy = gridDim.y, gz = gridDim.z;
    int w = xcd_remap((bz * gy + by) * gx + bx, gx * gy * gz);
    bx = w % gx; w /= gx; by = w % gy; bz = w / gy;
  }
  gemm_body<CF32, BM, BN, WRN, WCN, RING, SM, RELU, NRES>(P, bx, by, bz);
}

// ---------------------------------------------------------------------------
// Dual-problem GEMM kernel: blocks with remapped bx < split run p0, else p1.
// ---------------------------------------------------------------------------
template<int CF32, int BM, int BN, int WRN, int WCN, int RING,
         int SM, int RELU, int NRES, int SWZ>
__global__ __launch_bounds__(WRN * WCN * 64, 2)
void gemm2_k(GemmP p0, GemmP p1, int split)
{
  int bx = blockIdx.x, by = blockIdx.y, bz = blockIdx.z;
  if constexpr (SWZ == 1) {
    const int gx = gridDim.x, gy = gridDim.y;
    const int w = xcd_remap(by * gx + bx, gx * gy);
    bx = w / gy; by = w - bx * gy;
  } else if constexpr (SWZ == 2) {
    const int gx = gridDim.x, gy = gridDim.y, gz = gridDim.z;
    int w = xcd_remap((bz * gy + by) * gx + bx, gx * gy * gz);
    bx = w % gx; w /= gx; by = w % gy; bz = w / gy;
  }
  const bool first = (bx < split);
  const GemmP& P = first ? p0 : p1;
  if (!first) bx -= split;
  gemm_body<CF32, BM, BN, WRN, WCN, RING, SM, RELU, NRES>(P, bx, by, bz);
}

// ---------------------------------------------------------------------------
// Fused MHA with XCD-chunked block remap
// ---------------------------------------------------------------------------
__global__ __launch_bounds__(256, 2)
void mha_k(const short* __restrict__ Qp, long qStride,
           const short* __restrict__ Kp, long kStride, int ldk, int Lkv,
           const short* __restrict__ VTp, long vtStride,
           short* __restrict__ Op, int Lq, float alpha, int nvalid)
{
  __shared__ __align__(16) char smem[73728];
  char* Qs  = smem;
  char* Ks  = smem + 8192;
  char* VTs = smem + 40960;

  const int tid = threadIdx.x, lane = tid & 63, wid = tid >> 6;

  int bxr = blockIdx.x, bzr = blockIdx.z;
  {
    const int gx = gridDim.x, gz = gridDim.z;
    int w = xcd_remap(bzr * gx + bxr, gx * gz);
    bxr = w % gx; bzr = w / gx;
  }
  const int z = bzr, b = z >> 3, h = z & 7;
  const int m0 = bxr * 64;

  const short* Qb  = Qp + (long)b * qStride + h * 64;
  const short* Kb  = Kp + (long)b * kStride + h * 64;
  const short* VTb = VTp + (long)z * vtStride;
  short*       Ob  = Op + (long)b * qStride + h * 64;

#pragma unroll
  for (int j = 0; j < 2; ++j) {
    int chunk = (j * 4 + wid) * 64 + lane;
    int row = chunk >> 3, c = (chunk & 7) ^ (row & 7);
    int gr = m0 + row; if (gr > Lq - 1) gr = Lq - 1;
    gl_lds16(Qb + (long)gr * 512 + c * 8, Qs + chunk * 16);
  }
#pragma unroll
  for (int j = 0; j < 8; ++j) {
    int chunk = (j * 4 + wid) * 64 + lane;
    int row = chunk >> 3, c = (chunk & 7) ^ (row & 7);
    int gr = row; if (gr > Lkv - 1) gr = Lkv - 1;
    gl_lds16(Kb + (long)gr * ldk + c * 8, Ks + chunk * 16);
  }
#pragma unroll
  for (int j = 0; j < 8; ++j) {
    int chunk = (j * 4 + wid) * 64 + lane;
    int row = chunk >> 5, cw = (chunk & 31) ^ (row & 15);
    gl_lds16(VTb + (long)row * 256 + cw * 8, VTs + chunk * 16);
  }
  __syncthreads();

  f32x4 acc[16];
#pragma unroll
  for (int ni = 0; ni < 16; ++ni) acc[ni] = (f32x4){0.f, 0.f, 0.f, 0.f};
#pragma unroll
  for (int kk = 0; kk < 2; ++kk) {
    int kgr = kk * 4 + (lane >> 4);
    int m = wid * 16 + (lane & 15);
    s16x8 af = *(const s16x8*)(Qs + m * 128 + ((kgr ^ (m & 7)) << 4));
#pragma unroll
    for (int ni = 0; ni < 16; ++ni) {
      int n = ni * 16 + (lane & 15);
      s16x8 bf = *(const s16x8*)(Ks + n * 128 + ((kgr ^ (n & 7)) << 4));
      acc[ni] = __builtin_amdgcn_mfma_f32_16x16x32_bf16(af, bf, acc[ni], 0, 0, 0);
    }
  }

#pragma unroll
  for (int j = 0; j < 4; ++j) {
    float mx = -3.0e38f;
#pragma unroll
    for (int ni = 0; ni < 16; ++ni) {
      int col = ni * 16 + (lane & 15);
      float s = acc[ni][j] * alpha;
      acc[ni][j] = (col < nvalid) ? s : -3.0e38f;
      mx = fmaxf(mx, acc[ni][j]);
    }
#pragma unroll
    for (int o = 1; o < 16; o <<= 1) mx = fmaxf(mx, __shfl_xor(mx, o));
    float sum = 0.f;
#pragma unroll
    for (int ni = 0; ni < 16; ++ni) {
      int col = ni * 16 + (lane & 15);
      float e = (col < nvalid) ? __expf(acc[ni][j] - mx) : 0.f;
      acc[ni][j] = e;
      sum += e;
    }
#pragma unroll
    for (int o = 1; o < 16; o <<= 1) sum += __shfl_xor(sum, o);
    float inv = 1.f / sum;
#pragma unroll
    for (int ni = 0; ni < 16; ++ni) acc[ni][j] *= inv;
  }

  __syncthreads();

  {
    char* Ps = Ks + wid * 8192;
    const int r0 = (lane >> 4) * 4;
#pragma unroll
    for (int ni = 0; ni < 16; ++ni) {
      int col = ni * 16 + (lane & 15);
      int chunk = col >> 3, cin = (col & 7) * 2;
#pragma unroll
      for (int j = 0; j < 4; ++j) {
        int row = r0 + j;
        *(short*)(Ps + row * 512 + ((chunk ^ (row & 15)) << 4) + cin) = f2bf(acc[ni][j]);
      }
    }
  }
  asm volatile("s_waitcnt lgkmcnt(0)" ::: "memory");

  f32x4 acco[4];
#pragma unroll
  for (int ni = 0; ni < 4; ++ni) acco[ni] = (f32x4){0.f, 0.f, 0.f, 0.f};
  {
    const char* Ps = Ks + wid * 8192;
#pragma unroll
    for (int kk = 0; kk < 8; ++kk) {
      int g = lane >> 4;
      int mrow = lane & 15;
      int achunk = (kk * 4 + g) ^ (mrow & 15);
      s16x8 af = *(const s16x8*)(Ps + mrow * 512 + (achunk << 4));
#pragma unroll
      for (int ni = 0; ni < 4; ++ni) {
        int n = ni * 16 + (lane & 15);
        int bchunk = (kk * 4 + g) ^ (n & 15);
        s16x8 bf = *(const s16x8*)(VTs + n * 512 + (bchunk << 4));
        acco[ni] = __builtin_amdgcn_mfma_f32_16x16x32_bf16(af, bf, acco[ni], 0, 0, 0);
      }
    }
  }

  __syncthreads();

  {
    short* lh = (short*)smem;
#pragma unroll
    for (int ni = 0; ni < 4; ++ni) {
      int d = ni * 16 + (lane & 15);
      int rb = wid * 16 + ((lane >> 4) << 2);
#pragma unroll
      for (int j = 0; j < 4; ++j) lh[(rb + j) * 72 + d] = f2bf(acco[ni][j]);
    }
  }
  __syncthreads();
  {
    const int r0 = tid >> 3, cc = (tid & 7) * 8;
#pragma unroll
    for (int p = 0; p < 2; ++p) {
      int r = r0 + p * 32;
      int gr = m0 + r;
      if (gr < Lq) {
        s16x8 h8 = *(const s16x8*)((const short*)smem + r * 72 + cc);
        *(s16x8*)(Ob + (long)gr * 512 + cc) = h8;
      }
    }
  }
}

// ---------------------------------------------------------------------------
// Merged prep: weight transposes (z<16), x/text fp32->bf16 (z 16-31),
// x^T per-batch transpose (z 32-63). One dispatch.
// ---------------------------------------------------------------------------
__global__ __launch_bounds__(256)
void prep_k(const float* ftw, const float* fvw, const float* afw,
            const float* ftw1, const float* fvw1,
            const float* ftw2, const float* fvw2,
            const float* x, const float* text,
            short* wTbase, short* dW1, short* dW2,
            short* xbf, short* textbf, short* xT)
{
  const int z = blockIdx.y, zt = blockIdx.x;

  if (z >= 16 && z < 32) {
    long off = (long)(z & 7) * 524288 + (long)zt * 2048 + threadIdx.x * 8;
    const float* src = (z < 24 ? x : text) + off;
    short* dst = (z < 24 ? xbf : textbf) + off;
    f32x4 lo = *(const f32x4*)src, hi = *(const f32x4*)(src + 4);
    *(s16x8*)dst = cvt8(lo, hi);
    return;
  }

  __shared__ float tile[64][65];
  const float* in; short* out;
  int R_in, rs_in, Rpad, tiles_r;
  if (z < 12) {
    if (zt >= 64) return;
    const int grp = z >> 2, idx = z & 3;
    in = (grp == 0 ? ftw : grp == 1 ? fvw : afw) + (long)idx * 262144;
    out = wTbase + (long)grp * 3145728 + (long)idx * 262144;
    R_in = 512; rs_in = 512; Rpad = 512; tiles_r = 8;
  } else if (z < 14) {
    const int idx = z - 12;
    in = (idx == 0 ? ftw1 : fvw1);
    out = (idx == 0 ? dW1 : dW1 + 3145728);
    R_in = 512; rs_in = 2048; Rpad = 512; tiles_r = 8;
  } else if (z < 16) {
    const int idx = z - 14;
    in = (idx == 0 ? ftw2 : fvw2);
    out = (idx == 0 ? dW2 : dW2 + 3145728);
    R_in = 2048; rs_in = 512; Rpad = 2048; tiles_r = 32;
  } else {
    if (zt >= 32) return;
    const int b = z - 32;
    in = x + (long)b * 131072;
    out = xT + (long)b * 131072;
    R_in = 256; rs_in = 512; Rpad = 256; tiles_r = 4;
  }
  const int tr = zt % tiles_r, tc = zt / tiles_r;
  const int r0 = tr * 64, c0 = tc * 64;
  const int c = threadIdx.x & 63, l0 = threadIdx.x >> 6;

#pragma unroll 4
  for (int i = 0; i < 16; ++i) {
    int l = l0 + i * 4;
    int gr = r0 + l;
    float v = 0.f;
    if (gr < R_in) v = in[(long)gr * rs_in + c0 + c];
    tile[l][c] = v;
  }
  __syncthreads();
#pragma unroll 4
  for (int i = 0; i < 16; ++i) {
    int cr = l0 + i * 4;
    out[(long)(c0 + cr) * Rpad + r0 + c] = f2bf(tile[c][cr]);
  }
}

// ---------------------------------------------------------------------------
template<int RAW>
__global__ __launch_bounds__(256)
void ln_k(const float* __restrict__ in, const float* __restrict__ g,
          const float* __restrict__ b, short* __restrict__ outp,
          short* __restrict__ rawp, int rows)
{
  int row = blockIdx.x * 4 + (threadIdx.x >> 6);
  if (row >= rows) return;
  int lane = threadIdx.x & 63;
  const float* p = in + (long)row * 512 + lane * 8;
  f32x4 v0 = *(const f32x4*)p, v1 = *(const f32x4*)(p + 4);
  if constexpr (RAW) {
    short* rp = rawp + (long)row * 512 + lane * 8;
    *(s16x8*)rp = cvt8(v0, v1);
  }
  float s = 0.f, sq = 0.f;
#pragma unroll
  for (int j = 0; j < 4; ++j) { s += v0[j] + v1[j]; sq += v0[j]*v0[j] + v1[j]*v1[j]; }
#pragma unroll
  for (int o = 1; o < 64; o <<= 1) { s += __shfl_xor(s, o); sq += __shfl_xor(sq, o); }
  float mean = s * (1.f / 512.f);
  float var  = sq * (1.f / 512.f) - mean * mean;
  float rs   = rsqrtf(var + 1e-6f);
  const f32x4 g0 = *(const f32x4*)(g + lane * 8), g1 = *(const f32x4*)(g + lane * 8 + 4);
  const f32x4 b0 = *(const f32x4*)(b + lane * 8), b1 = *(const f32x4*)(b + lane * 8 + 4);
  f32x4 o0, o1;
#pragma unroll
  for (int j = 0; j < 4; ++j) {
    o0[j] = g0[j] * (v0[j] - mean) * rs + b0[j];
    o1[j] = g1[j] * (v1[j] - mean) * rs + b1[j];
  }
  short* op = outp + (long)row * 512 + lane * 8;
  *(s16x8*)op = cvt8(o0, o1);
}

// ---------------------------------------------------------------------------
static GemmP mkP(const short* A, int hbA, long sAo, long sAi, int lda,
                 const short* B, int hbB, long sBo, long sBi, int ldb,
                 void* C, int hbC, long sCo, long sCi, int ldc,
                 const float* bias, const float* r1, const float* r2,
                 int M, int N, int K, float alpha, int nvalid, int biasm = 0)
{
  GemmP P;
  P.A = A; P.hbA = hbA; P.sAo = sAo; P.sAi = sAi; P.lda = lda;
  P.B = B; P.hbB = hbB; P.sBo = sBo; P.sBi = sBi; P.ldb = ldb;
  P.C = C; P.hbC = hbC; P.sCo = sCo; P.sCi = sCi; P.ldc = ldc;
  P.bias = bias; P.res1 = r1; P.res2 = r2;
  P.M = M; P.N = N; P.K = K; P.alpha = alpha; P.nvalid = nvalid;
  P.biasm = biasm;
  return P;
}

extern "C" void kernel_launch(void* const* d_in, const int* in_sizes, int n_in,
                              void* d_out, int out_size, void* d_ws, size_t ws_size,
                              hipStream_t stream)
{
  (void)in_sizes; (void)n_in; (void)out_size; (void)ws_size;

  const float* x     = (const float*)d_in[0];
  const float* text  = (const float*)d_in[1];
  const float* vis   = (const float*)d_in[2];
  const float* ftw   = (const float*)d_in[3];
  const float* ftb   = (const float*)d_in[4];
  const float* ftw1  = (const float*)d_in[5];
  const float* ftb1  = (const float*)d_in[6];
  const float* ftw2  = (const float*)d_in[7];
  const float* ftb2  = (const float*)d_in[8];
  const float* ftln  = (const float*)d_in[9];
  const float* fvw   = (const float*)d_in[10];
  const float* fvb   = (const float*)d_in[11];
  const float* fvw1  = (const float*)d_in[12];
  const float* fvb1  = (const float*)d_in[13];
  const float* fvw2  = (const float*)d_in[14];
  const float* fvb2  = (const float*)d_in[15];
  const float* fvln  = (const float*)d_in[16];
  const float* ldmln = (const float*)d_in[17];
  const float* afw   = (const float*)d_in[18];
  const float* afb   = (const float*)d_in[19];
  float* out = (float*)d_out;

  char* ws = (char*)d_ws;
  short* wT     = (short*)ws;
  short* xbf    = (short*)(ws + 14680064);
  short* bufLN  = (short*)(ws + 23068672);
  short* bufQ   = (short*)(ws + 29491200);
  short* bufKV  = (short*)(ws + 37879808);
  short* bufT   = (short*)(ws + 54657024);
  short* bufS   = (short*)(ws + 63045632);
  short* bufO   = (short*)(ws + 88735744);
  float* bufX1  = (float*)(ws + 97124352);
  float* bufA2  = (float*)(ws + 109969408);
  short* bufMED = (short*)(ws + 122814464);
  short* bufT2  = (short*)(ws + 129236992);   // x^T, 8,388,608 B
  short* textbf = bufO;
  short* visbf  = (short*)bufA2;
  short* bufSD  = bufS + 2097152;             // D-scores region

  short* ftWq  = wT + 0;
  short* ftWk  = wT + 262144;
  short* ftWv  = wT + 524288;
  short* ftWo  = wT + 786432;
  short* ftW1t = wT + 1048576;
  short* ftW2t = wT + 2097152;
  short* fvWq  = wT + 3145728;
  short* fvWk  = wT + 3407872;
  short* fvWv  = wT + 3670016;
  short* fvWo  = wT + 3932160;
  short* fvW1t = wT + 4194304;
  short* fvW2t = wT + 5242880;
  short* afW00 = wT + 6291456;
  short* afW01 = wT + 6553600;
  short* afW10 = wT + 6815744;
  short* afW11 = wT + 7077888;

  const float AFS = 0.04419417382415922f;
  dim3 blk(256);

  // ---- prep: single merged dispatch (weights + converts + x^T) ----
  prep_k<<<dim3(256, 64), blk, 0, stream>>>(
      ftw, fvw, afw, ftw1, fvw1, ftw2, fvw2, x, text,
      wT, ftW1t, ftW2t, xbf, textbf, bufT2);

  // ================= Phase A: cross_layer(vis, text, ft) =================
  ln_k<1><<<1568, blk, 0, stream>>>(vis, ftln + 0, ftln + 512, bufLN, visbf, 6272);
  // merged Q-proj + K-proj
  gemm2_k<0,128,64,2,2,3,0,0,0,1><<<dim3(113,8,1), blk, 0, stream>>>(
      mkP(bufLN,1,0,0,512, ftWq,1,0,0,512, bufQ,1,0,0,512,
          ftb + 0, nullptr, nullptr, 6272,512,512, 1.f, 0),
      mkP(textbf,1,0,0,512, ftWk,1,0,0,512, bufKV,1,0,0,512,
          ftb + 512, nullptr, nullptr, 8192,512,512, 1.f, 0), 49);
  gemm_k<0,128,64,2,2,3,0,0,0,2><<<dim3(4,4,32), blk, 0, stream>>>(
      mkP(ftWv,1,0,0,512, textbf,1,131072L,0L,512, bufT,1,131072L,0L,256,
          ftb + 1024, nullptr, nullptr, 512,256,512, 1.f, 0, 1));
  mha_k<<<dim3(4,1,256), blk, 0, stream>>>(bufQ, 100352L, bufKV, 131072L, 512, 256,
      bufT, 16384L, bufO, 196, 0.125f, 256);
  gemm_k<1,128,64,2,2,3,0,0,1,1><<<dim3(49,8,1), blk, 0, stream>>>(
      mkP(bufO,1,0,0,512, ftWo,1,0,0,512, bufX1,1,0,0,512,
          ftb + 1536, vis, nullptr, 6272,512,512, 1.f, 0));
  ln_k<0><<<1568, blk, 0, stream>>>(bufX1, ftln + 1024, ftln + 1536, bufLN, nullptr, 6272);
  gemm_k<0,128,128,2,2,2,0,1,0,1><<<dim3(49,16,1), blk, 0, stream>>>(
      mkP(bufLN,1,0,0,512, ftW1t,1,0,0,512, bufS,1,0,0,2048,
          ftb1, nullptr, nullptr, 6272,2048,512, 1.f, 0));
  gemm_k<1,128,64,2,2,3,0,0,1,1><<<dim3(49,8,1), blk, 0, stream>>>(
      mkP(bufS,1,0,0,2048, ftW2t,1,0,0,2048, bufX1,1,0,0,512,
          ftb2, bufX1, nullptr, 6272,512,2048, 1.f, 0));

  // ================= Phase B: cross_layer(med1, vis, fv) + med1 =================
  ln_k<0><<<1568, blk, 0, stream>>>(bufX1, fvln + 0, fvln + 512, bufLN, nullptr, 6272);
  gemm2_k<0,128,64,2,2,3,0,0,0,1><<<dim3(98,8,1), blk, 0, stream>>>(
      mkP(bufLN,1,0,0,512, fvWq,1,0,0,512, bufQ,1,0,0,512,
          fvb + 0, nullptr, nullptr, 6272,512,512, 1.f, 0),
      mkP(visbf,1,0,0,512, fvWk,1,0,0,512, bufKV,1,0,0,512,
          fvb + 512, nullptr, nullptr, 6272,512,512, 1.f, 0), 49);
  gemm_k<0,128,64,2,2,3,0,0,0,2><<<dim3(4,4,32), blk, 0, stream>>>(
      mkP(fvWv,1,0,0,512, visbf,1,100352L,0L,512, bufT,1,131072L,0L,256,
          fvb + 1024, nullptr, nullptr, 512,196,512, 1.f, 0, 1));
  mha_k<<<dim3(4,1,256), blk, 0, stream>>>(bufQ, 100352L, bufKV, 100352L, 512, 196,
      bufT, 16384L, bufO, 196, 0.125f, 196);
  gemm_k<1,128,64,2,2,3,0,0,1,1><<<dim3(49,8,1), blk, 0, stream>>>(
      mkP(bufO,1,0,0,512, fvWo,1,0,0,512, bufA2,1,0,0,512,
          fvb + 1536, bufX1, nullptr, 6272,512,512, 1.f, 0));
  ln_k<0><<<1568, blk, 0, stream>>>(bufA2, fvln + 1024, fvln + 1536, bufLN, nullptr, 6272);
  gemm_k<0,128,128,2,2,2,0,1,0,1><<<dim3(49,16,1), blk, 0, stream>>>(
      mkP(bufLN,1,0,0,512, fvW1t,1,0,0,512, bufS,1,0,0,2048,
          fvb1, nullptr, nullptr, 6272,2048,512, 1.f, 0));
  gemm_k<1,128,64,2,2,3,0,0,2,1><<<dim3(49,8,1), blk, 0, stream>>>(
      mkP(bufS,1,0,0,2048, fvW2t,1,0,0,2048, bufA2,1,0,0,512,
          fvb2, bufA2, bufX1, 6272,512,2048, 1.f, 0));
  ln_k<0><<<1568, blk, 0, stream>>>(bufA2, ldmln + 0, ldmln + 512, bufMED, nullptr, 6272);

  // ============ Phases C+D interleaved: v_af then out ============
  gemm2_k<0,128,64,2,2,3,0,0,0,1><<<dim3(113,8,1), blk, 0, stream>>>(
      mkP(bufMED,1,0,0,512, afW00,1,0,0,512, bufQ,1,0,0,512,
          afb + 0, nullptr, nullptr, 6272,512,512, 1.f, 0),
      mkP(xbf,1,0,0,512, afW10,1,0,0,512, bufKV,1,0,0,512,
          afb + 1024, nullptr, nullptr, 8192,512,512, 1.f, 0), 49);
  gemm2_k<0,32,256,2,1,2,1,0,0,2><<<dim3(15,1,32), dim3(128), 0, stream>>>(
      mkP(bufQ,1,100352L,0L,512, xbf,1,131072L,0L,512, bufS,1,50176L,0L,256,
          nullptr, nullptr, nullptr, 196,256,512, AFS, 256),
      mkP(bufKV,1,131072L,0L,512, bufMED,1,100352L,0L,512, bufSD,1,65536L,0L,256,
          nullptr, nullptr, nullptr, 256,256,512, AFS, 196), 7);
  gemm_k<0,64,128,2,2,3,0,0,0,2><<<dim3(4,4,32), blk, 0, stream>>>(
      mkP(bufS,1,50176L,0L,256, bufT2,1,131072L,0L,256, bufO,1,100352L,0L,512,
          nullptr, nullptr, nullptr, 196,512,256, 1.f, 0));
  gemm_k<0,128,64,2,2,3,0,0,0,2><<<dim3(4,4,32), blk, 0, stream>>>(
      mkP(afW01,1,0,0,512, bufO,1,100352L,0L,512, bufT,1,131072L,0L,256,
          afb + 512, nullptr, nullptr, 512,256,512, 1.f, 0, 1));
  gemm_k<0,64,128,2,2,3,0,0,0,2><<<dim3(4,4,32), blk, 0, stream>>>(
      mkP(bufSD,1,65536L,0L,256, bufT,1,131072L,0L,256, bufO,1,131072L,0L,512,
          nullptr, nullptr, nullptr, 256,512,256, 1.f, 0));
  gemm_k<1,128,64,2,2,3,0,0,1,1><<<dim3(64,8,1), blk, 0, stream>>>(
      mkP(bufO,1,0,0,512, afW11,1,0,0,512, out,1,0,0,512,
          afb + 1536, x, nullptr, 8192,512,512, 1.f, 0));
}

// Round 16
// 338.469 us; speedup vs baseline: 1.0146x; 1.0146x over previous
//
#include <hip/hip_runtime.h>
#include <hip/hip_bf16.h>

typedef __attribute__((ext_vector_type(4))) float f32x4;
typedef __attribute__((ext_vector_type(8))) short s16x8;
typedef __attribute__((ext_vector_type(4))) short s16x4;

__device__ __forceinline__ short f2bf(float f) {
  union { float f; unsigned u; } c; c.f = f;
  unsigned r = c.u + 0x7fffu + ((c.u >> 16) & 1u);
  return (short)(r >> 16);
}
__device__ __forceinline__ float bf2f(short h) {
  union { unsigned u; float f; } c; c.u = ((unsigned)(unsigned short)h) << 16;
  return c.f;
}
__device__ __forceinline__ s16x8 cvt8(const f32x4& lo, const f32x4& hi) {
  s16x8 v;
  v[0] = f2bf(lo[0]); v[1] = f2bf(lo[1]); v[2] = f2bf(lo[2]); v[3] = f2bf(lo[3]);
  v[4] = f2bf(hi[0]); v[5] = f2bf(hi[1]); v[6] = f2bf(hi[2]); v[7] = f2bf(hi[3]);
  return v;
}

__device__ __forceinline__ void gl_lds16(const short* g, char* l) {
  __builtin_amdgcn_global_load_lds(
      (const __attribute__((address_space(1))) unsigned int*)g,
      (__attribute__((address_space(3))) unsigned int*)l, 16, 0, 0);
}

// ---------------------------------------------------------------------------
// Runtime parameter pack for one GEMM problem
// ---------------------------------------------------------------------------
struct GemmP {
  const short* A; int hbA; long sAo, sAi; int lda;
  const short* B; int hbB; long sBo, sBi; int ldb;
  void* C; int hbC; long sCo, sCi; int ldc;
  const float* bias; const float* res1; const float* res2;
  int M, N, K; float alpha; int nvalid;
};

// ---------------------------------------------------------------------------
// GEMM body (all-bf16 in): C = alpha*A[M,K]@B[N,K]^T (+bias/res/softmax)
// ---------------------------------------------------------------------------
template<int CF32, int BM, int BN, int WRN, int WCN, int RING,
         int SM, int RELU, int NRES, int BIASM>
__device__ __forceinline__
void gemm_body(const GemmP& P, int bx, int by, int bz)
{
  constexpr int WAVES = WRN * WCN;
  constexpr int T = WAVES * 64;
  constexpr int MI = BM / (WRN * 16), NI = BN / (WCN * 16);
  constexpr int ACH = BM * 8 / T, BCH = BN * 8 / T;
  constexpr int L   = ACH + BCH;
  constexpr int ABYTES = BM * 128;
  constexpr int TBYTES = (BM + BN) * 128;
  constexpr int LSTR = BN + (CF32 ? 4 : 8);
  constexpr int EPIB = BM * LSTR * (CF32 ? 4 : 2);
  constexpr int SMEMB = (RING * TBYTES > EPIB) ? RING * TBYTES : EPIB;
  __shared__ __align__(16) char smem[SMEMB];

  const int tid  = threadIdx.x;
  const int lane = tid & 63;
  const int wid  = tid >> 6;
  const int wr   = wid / WCN, wc = wid % WCN;

  const int m0 = bx * BM, n0 = by * BN;
  const int z  = bz;

  const int zA = z / P.hbA, zAi = z - zA * P.hbA;
  const int zB = z / P.hbB, zBi = z - zB * P.hbB;
  const int zC = z / P.hbC, zCi = z - zC * P.hbC;
  const short* Ab = P.A + (long)zA * P.sAo + (long)zAi * P.sAi;
  const short* Bb = P.B + (long)zB * P.sBo + (long)zBi * P.sBi;
  char*        Cb = (char*)P.C + ((long)zC * P.sCo + (long)zCi * P.sCi) * (CF32 ? 4 : 2);

  int aL[ACH]; long aG[ACH];
#pragma unroll
  for (int j = 0; j < ACH; ++j) {
    int chunk = (j * WAVES + wid) * 64 + lane;
    int row = chunk >> 3;
    int c   = (chunk & 7) ^ (row & 7);
    int gr = m0 + row; if (gr > P.M - 1) gr = P.M - 1;
    aL[j] = chunk * 16;
    aG[j] = (long)gr * P.lda + c * 8;
  }
  int bL[BCH]; long bG[BCH];
#pragma unroll
  for (int j = 0; j < BCH; ++j) {
    int chunk = (j * WAVES + wid) * 64 + lane;
    int row = chunk >> 3;
    int c   = (chunk & 7) ^ (row & 7);
    int gc = n0 + row; if (gc > P.N - 1) gc = P.N - 1;
    bL[j] = chunk * 16;
    bG[j] = (long)gc * P.ldb + c * 8;
  }

  auto stage = [&](int buf, int kt) {
    const short* Akt = Ab + (long)kt * 64;
    char* base = smem + buf * TBYTES;
#pragma unroll
    for (int j = 0; j < ACH; ++j) gl_lds16(Akt + aG[j], base + aL[j]);
    const short* Bkt = Bb + (long)kt * 64;
#pragma unroll
    for (int j = 0; j < BCH; ++j) gl_lds16(Bkt + bG[j], base + ABYTES + bL[j]);
  };

  int ard[2][MI], brd[2][NI];
#pragma unroll
  for (int kk = 0; kk < 2; ++kk) {
    int kgr = kk * 4 + (lane >> 4);
#pragma unroll
    for (int mi = 0; mi < MI; ++mi) {
      int m = wr * (BM / WRN) + mi * 16 + (lane & 15);
      ard[kk][mi] = m * 128 + ((kgr ^ (m & 7)) << 4);
    }
#pragma unroll
    for (int ni = 0; ni < NI; ++ni) {
      int n = wc * (BN / WCN) + ni * 16 + (lane & 15);
      brd[kk][ni] = ABYTES + n * 128 + ((kgr ^ (n & 7)) << 4);
    }
  }

  const int NT = P.K >> 6;
#pragma unroll
  for (int p = 0; p < RING; ++p) if (p < NT) stage(p, p);

  f32x4 acc[MI][NI];
#pragma unroll
  for (int mi = 0; mi < MI; ++mi)
#pragma unroll
    for (int ni = 0; ni < NI; ++ni) acc[mi][ni] = (f32x4){0.f, 0.f, 0.f, 0.f};

  int bufi = 0;
  for (int t = 0; t < NT; ++t) {
    const int rem = NT - t;
    if constexpr (RING == 3) {
      if (rem >= 3)      asm volatile("s_waitcnt vmcnt(%0)" :: "n"(2 * L) : "memory");
      else if (rem == 2) asm volatile("s_waitcnt vmcnt(%0)" :: "n"(L) : "memory");
      else               asm volatile("s_waitcnt vmcnt(0)" ::: "memory");
    } else if constexpr (RING == 2) {
      if (rem >= 2)      asm volatile("s_waitcnt vmcnt(%0)" :: "n"(L) : "memory");
      else               asm volatile("s_waitcnt vmcnt(0)" ::: "memory");
    } else {
      asm volatile("s_waitcnt vmcnt(0)" ::: "memory");
    }
    asm volatile("s_barrier" ::: "memory");

    const char* base = smem + bufi * TBYTES;
#pragma unroll
    for (int kk = 0; kk < 2; ++kk) {
      s16x8 af[MI];
#pragma unroll
      for (int mi = 0; mi < MI; ++mi) af[mi] = *(const s16x8*)(base + ard[kk][mi]);
#pragma unroll
      for (int ni = 0; ni < NI; ++ni) {
        s16x8 bf = *(const s16x8*)(base + brd[kk][ni]);
#pragma unroll
        for (int mi = 0; mi < MI; ++mi)
          acc[mi][ni] = __builtin_amdgcn_mfma_f32_16x16x32_bf16(af[mi], bf, acc[mi][ni], 0, 0, 0);
      }
    }

    if (t + RING < NT) {
      asm volatile("s_waitcnt lgkmcnt(0)" ::: "memory");
      asm volatile("s_barrier" ::: "memory");
      stage(bufi, t + RING);
    }
    bufi = (bufi + 1 == RING) ? 0 : bufi + 1;
  }

  if constexpr (SM) {
#pragma unroll
    for (int mi = 0; mi < MI; ++mi) {
#pragma unroll
      for (int j = 0; j < 4; ++j) {
        float mx = -3.0e38f;
#pragma unroll
        for (int ni = 0; ni < NI; ++ni) {
          int col = n0 + wc * (BN / WCN) + ni * 16 + (lane & 15);
          float s = acc[mi][ni][j] * P.alpha;
          acc[mi][ni][j] = (col < P.nvalid) ? s : -3.0e38f;
          mx = fmaxf(mx, acc[mi][ni][j]);
        }
#pragma unroll
        for (int o = 1; o < 16; o <<= 1) mx = fmaxf(mx, __shfl_xor(mx, o));
        float sum = 0.f;
#pragma unroll
        for (int ni = 0; ni < NI; ++ni) {
          int col = n0 + wc * (BN / WCN) + ni * 16 + (lane & 15);
          float e = (col < P.nvalid) ? __expf(acc[mi][ni][j] - mx) : 0.f;
          acc[mi][ni][j] = e;
          sum += e;
        }
#pragma unroll
        for (int o = 1; o < 16; o <<= 1) sum += __shfl_xor(sum, o);
        float inv = 1.f / sum;
#pragma unroll
        for (int ni = 0; ni < NI; ++ni) acc[mi][ni][j] *= inv;
      }
    }
  }
  const float aep = SM ? 1.f : P.alpha;

  asm volatile("s_waitcnt lgkmcnt(0)" ::: "memory");
  __syncthreads();

  {
    float* lf = (float*)smem;
    short* lh = (short*)smem;
#pragma unroll
    for (int mi = 0; mi < MI; ++mi)
#pragma unroll
      for (int ni = 0; ni < NI; ++ni) {
        int c_loc = wc * (BN / WCN) + ni * 16 + (lane & 15);
        float bv = (P.bias && !BIASM) ? P.bias[n0 + c_loc] : 0.f;
        int rb = wr * (BM / WRN) + mi * 16 + ((lane >> 4) << 2);
#pragma unroll
        for (int j = 0; j < 4; ++j) {
          float v = acc[mi][ni][j] * aep + bv;
          if constexpr (CF32) lf[(rb + j) * LSTR + c_loc] = v;
          else                lh[(rb + j) * LSTR + c_loc] = f2bf(v);
        }
      }
  }
  __syncthreads();

  constexpr int CPR = BN / 8;
  constexpr int RP  = T / CPR;
  const int rr0 = tid / CPR;
  const int cc  = (tid % CPR) * 8;
  for (int r = rr0; r < BM; r += RP) {
    const int gr = m0 + r;
    if (gr >= P.M) break;
    f32x4 a, b;
    if constexpr (CF32) {
      a = *(const f32x4*)((const float*)smem + (long)r * LSTR + cc);
      b = *(const f32x4*)((const float*)smem + (long)r * LSTR + cc + 4);
    } else {
      s16x8 h = *(const s16x8*)((const short*)smem + (long)r * LSTR + cc);
#pragma unroll
      for (int j = 0; j < 4; ++j) { a[j] = bf2f(h[j]); b[j] = bf2f(h[j + 4]); }
    }
    if constexpr (BIASM) {
      float bm = P.bias[gr];
#pragma unroll
      for (int j = 0; j < 4; ++j) { a[j] += bm; b[j] += bm; }
    }
    const long gb = (long)gr * P.ldc + n0 + cc;
    if constexpr (NRES >= 1) {
      f32x4 r1 = *(const f32x4*)(P.res1 + gb), r2 = *(const f32x4*)(P.res1 + gb + 4);
#pragma unroll
      for (int j = 0; j < 4; ++j) { a[j] += r1[j]; b[j] += r2[j]; }
    }
    if constexpr (NRES >= 2) {
      f32x4 r1 = *(const f32x4*)(P.res2 + gb), r2 = *(const f32x4*)(P.res2 + gb + 4);
#pragma unroll
      for (int j = 0; j < 4; ++j) { a[j] += r1[j]; b[j] += r2[j]; }
    }
    if constexpr (RELU) {
#pragma unroll
      for (int j = 0; j < 4; ++j) { a[j] = fmaxf(a[j], 0.f); b[j] = fmaxf(b[j], 0.f); }
    }
    if constexpr (CF32) {
      *(f32x4*)((float*)Cb + gb) = a;
      *(f32x4*)((float*)Cb + gb + 4) = b;
    } else {
      *(s16x8*)((short*)Cb + gb) = cvt8(a, b);
    }
  }
}

// XCD-chunked bijective remap over a linear id
__device__ __forceinline__ int xcd_remap(int o, int nwg)
{
  const int q = nwg >> 3, r = nwg & 7;
  const int xcd = o & 7, slot = o >> 3;
  return (xcd < r ? xcd * (q + 1) : r * (q + 1) + (xcd - r) * q) + slot;
}

// ---------------------------------------------------------------------------
// Single-problem GEMM kernel
// ---------------------------------------------------------------------------
template<int CF32, int BM, int BN, int WRN, int WCN, int RING,
         int SM, int RELU, int NRES, int BIASM, int SWZ>
__global__ __launch_bounds__(WRN * WCN * 64, 2)
void gemm_k(GemmP P)
{
  int bx = blockIdx.x, by = blockIdx.y, bz = blockIdx.z;
  if constexpr (SWZ == 1) {
    const int gx = gridDim.x, gy = gridDim.y;
    const int w = xcd_remap(by * gx + bx, gx * gy);
    bx = w / gy; by = w - bx * gy;
  } else if constexpr (SWZ == 2) {
    const int gx = gridDim.x, gy = gridDim.y, gz = gridDim.z;
    int w = xcd_remap((bz * gy + by) * gx + bx, gx * gy * gz);
    bx = w % gx; w /= gx; by = w % gy; bz = w / gy;
  }
  gemm_body<CF32, BM, BN, WRN, WCN, RING, SM, RELU, NRES, BIASM>(P, bx, by, bz);
}

// ---------------------------------------------------------------------------
// Dual-problem GEMM kernel: blocks with remapped bx < split run p0, else p1.
// ---------------------------------------------------------------------------
template<int CF32, int BM, int BN, int WRN, int WCN, int RING,
         int SM, int RELU, int NRES, int BIASM, int SWZ>
__global__ __launch_bounds__(WRN * WCN * 64, 2)
void gemm2_k(GemmP p0, GemmP p1, int split)
{
  int bx = blockIdx.x, by = blockIdx.y, bz = blockIdx.z;
  if constexpr (SWZ == 1) {
    const int gx = gridDim.x, gy = gridDim.y;
    const int w = xcd_remap(by * gx + bx, gx * gy);
    bx = w / gy; by = w - bx * gy;
  } else if constexpr (SWZ == 2) {
    const int gx = gridDim.x, gy = gridDim.y, gz = gridDim.z;
    int w = xcd_remap((bz * gy + by) * gx + bx, gx * gy * gz);
    bx = w % gx; w /= gx; by = w % gy; bz = w / gy;
  }
  const bool first = (bx < split);
  const GemmP& P = first ? p0 : p1;
  if (!first) bx -= split;
  gemm_body<CF32, BM, BN, WRN, WCN, RING, SM, RELU, NRES, BIASM>(P, bx, by, bz);
}

// ---------------------------------------------------------------------------
// Fused MHA with XCD-chunked block remap
// ---------------------------------------------------------------------------
__global__ __launch_bounds__(256, 2)
void mha_k(const short* __restrict__ Qp, long qStride,
           const short* __restrict__ Kp, long kStride, int ldk, int Lkv,
           const short* __restrict__ VTp, long vtStride,
           short* __restrict__ Op, int Lq, float alpha, int nvalid)
{
  __shared__ __align__(16) char smem[73728];
  char* Qs  = smem;
  char* Ks  = smem + 8192;
  char* VTs = smem + 40960;

  const int tid = threadIdx.x, lane = tid & 63, wid = tid >> 6;

  int bxr = blockIdx.x, bzr = blockIdx.z;
  {
    const int gx = gridDim.x, gz = gridDim.z;
    int w = xcd_remap(bzr * gx + bxr, gx * gz);
    bxr = w % gx; bzr = w / gx;
  }
  const int z = bzr, b = z >> 3, h = z & 7;
  const int m0 = bxr * 64;

  const short* Qb  = Qp + (long)b * qStride + h * 64;
  const short* Kb  = Kp + (long)b * kStride + h * 64;
  const short* VTb = VTp + (long)z * vtStride;
  short*       Ob  = Op + (long)b * qStride + h * 64;

#pragma unroll
  for (int j = 0; j < 2; ++j) {
    int chunk = (j * 4 + wid) * 64 + lane;
    int row = chunk >> 3, c = (chunk & 7) ^ (row & 7);
    int gr = m0 + row; if (gr > Lq - 1) gr = Lq - 1;
    gl_lds16(Qb + (long)gr * 512 + c * 8, Qs + chunk * 16);
  }
#pragma unroll
  for (int j = 0; j < 8; ++j) {
    int chunk = (j * 4 + wid) * 64 + lane;
    int row = chunk >> 3, c = (chunk & 7) ^ (row & 7);
    int gr = row; if (gr > Lkv - 1) gr = Lkv - 1;
    gl_lds16(Kb + (long)gr * ldk + c * 8, Ks + chunk * 16);
  }
#pragma unroll
  for (int j = 0; j < 8; ++j) {
    int chunk = (j * 4 + wid) * 64 + lane;
    int row = chunk >> 5, cw = (chunk & 31) ^ (row & 15);
    gl_lds16(VTb + (long)row * 256 + cw * 8, VTs + chunk * 16);
  }
  __syncthreads();

  f32x4 acc[16];
#pragma unroll
  for (int ni = 0; ni < 16; ++ni) acc[ni] = (f32x4){0.f, 0.f, 0.f, 0.f};
#pragma unroll
  for (int kk = 0; kk < 2; ++kk) {
    int kgr = kk * 4 + (lane >> 4);
    int m = wid * 16 + (lane & 15);
    s16x8 af = *(const s16x8*)(Qs + m * 128 + ((kgr ^ (m & 7)) << 4));
#pragma unroll
    for (int ni = 0; ni < 16; ++ni) {
      int n = ni * 16 + (lane & 15);
      s16x8 bf = *(const s16x8*)(Ks + n * 128 + ((kgr ^ (n & 7)) << 4));
      acc[ni] = __builtin_amdgcn_mfma_f32_16x16x32_bf16(af, bf, acc[ni], 0, 0, 0);
    }
  }

#pragma unroll
  for (int j = 0; j < 4; ++j) {
    float mx = -3.0e38f;
#pragma unroll
    for (int ni = 0; ni < 16; ++ni) {
      int col = ni * 16 + (lane & 15);
      float s = acc[ni][j] * alpha;
      acc[ni][j] = (col < nvalid) ? s : -3.0e38f;
      mx = fmaxf(mx, acc[ni][j]);
    }
#pragma unroll
    for (int o = 1; o < 16; o <<= 1) mx = fmaxf(mx, __shfl_xor(mx, o));
    float sum = 0.f;
#pragma unroll
    for (int ni = 0; ni < 16; ++ni) {
      int col = ni * 16 + (lane & 15);
      float e = (col < nvalid) ? __expf(acc[ni][j] - mx) : 0.f;
      acc[ni][j] = e;
      sum += e;
    }
#pragma unroll
    for (int o = 1; o < 16; o <<= 1) sum += __shfl_xor(sum, o);
    float inv = 1.f / sum;
#pragma unroll
    for (int ni = 0; ni < 16; ++ni) acc[ni][j] *= inv;
  }

  __syncthreads();

  {
    char* Ps = Ks + wid * 8192;
    const int r0 = (lane >> 4) * 4;
#pragma unroll
    for (int ni = 0; ni < 16; ++ni) {
      int col = ni * 16 + (lane & 15);
      int chunk = col >> 3, cin = (col & 7) * 2;
#pragma unroll
      for (int j = 0; j < 4; ++j) {
        int row = r0 + j;
        *(short*)(Ps + row * 512 + ((chunk ^ (row & 15)) << 4) + cin) = f2bf(acc[ni][j]);
      }
    }
  }
  asm volatile("s_waitcnt lgkmcnt(0)" ::: "memory");

  f32x4 acco[4];
#pragma unroll
  for (int ni = 0; ni < 4; ++ni) acco[ni] = (f32x4){0.f, 0.f, 0.f, 0.f};
  {
    const char* Ps = Ks + wid * 8192;
#pragma unroll
    for (int kk = 0; kk < 8; ++kk) {
      int g = lane >> 4;
      int mrow = lane & 15;
      int achunk = (kk * 4 + g) ^ (mrow & 15);
      s16x8 af = *(const s16x8*)(Ps + mrow * 512 + (achunk << 4));
#pragma unroll
      for (int ni = 0; ni < 4; ++ni) {
        int n = ni * 16 + (lane & 15);
        int bchunk = (kk * 4 + g) ^ (n & 15);
        s16x8 bf = *(const s16x8*)(VTs + n * 512 + (bchunk << 4));
        acco[ni] = __builtin_amdgcn_mfma_f32_16x16x32_bf16(af, bf, acco[ni], 0, 0, 0);
      }
    }
  }

  __syncthreads();

  {
    short* lh = (short*)smem;
#pragma unroll
    for (int ni = 0; ni < 4; ++ni) {
      int d = ni * 16 + (lane & 15);
      int rb = wid * 16 + ((lane >> 4) << 2);
#pragma unroll
      for (int j = 0; j < 4; ++j) lh[(rb + j) * 72 + d] = f2bf(acco[ni][j]);
    }
  }
  __syncthreads();
  {
    const int r0 = tid >> 3, cc = (tid & 7) * 8;
#pragma unroll
    for (int p = 0; p < 2; ++p) {
      int r = r0 + p * 32;
      int gr = m0 + r;
      if (gr < Lq) {
        s16x8 h8 = *(const s16x8*)((const short*)smem + r * 72 + cc);
        *(s16x8*)(Ob + (long)gr * 512 + cc) = h8;
      }
    }
  }
}

// ---------------------------------------------------------------------------
// Merged prep: weight transposes (z<16), x/text fp32->bf16 (z 16-31),
// x^T per-batch transpose (z 32-63). One dispatch.
// ---------------------------------------------------------------------------
__global__ __launch_bounds__(256)
void prep_k(const float* ftw, const float* fvw, const float* afw,
            const float* ftw1, const float* fvw1,
            const float* ftw2, const float* fvw2,
            const float* x, const float* text,
            short* wTbase, short* dW1, short* dW2,
            short* xbf, short* textbf, short* xT)
{
  const int z = blockIdx.y, zt = blockIdx.x;

  if (z >= 16 && z < 32) {
    long off = (long)(z & 7) * 524288 + (long)zt * 2048 + threadIdx.x * 8;
    const float* src = (z < 24 ? x : text) + off;
    short* dst = (z < 24 ? xbf : textbf) + off;
    f32x4 lo = *(const f32x4*)src, hi = *(const f32x4*)(src + 4);
    *(s16x8*)dst = cvt8(lo, hi);
    return;
  }

  __shared__ float tile[64][65];
  const float* in; short* out;
  int R_in, rs_in, Rpad, tiles_r;
  if (z < 12) {
    if (zt >= 64) return;
    const int grp = z >> 2, idx = z & 3;
    in = (grp == 0 ? ftw : grp == 1 ? fvw : afw) + (long)idx * 262144;
    out = wTbase + (long)grp * 3145728 + (long)idx * 262144;
    R_in = 512; rs_in = 512; Rpad = 512; tiles_r = 8;
  } else if (z < 14) {
    const int idx = z - 12;
    in = (idx == 0 ? ftw1 : fvw1);
    out = (idx == 0 ? dW1 : dW1 + 3145728);
    R_in = 512; rs_in = 2048; Rpad = 512; tiles_r = 8;
  } else if (z < 16) {
    const int idx = z - 14;
    in = (idx == 0 ? ftw2 : fvw2);
    out = (idx == 0 ? dW2 : dW2 + 3145728);
    R_in = 2048; rs_in = 512; Rpad = 2048; tiles_r = 32;
  } else {
    if (zt >= 32) return;
    const int b = z - 32;
    in = x + (long)b * 131072;
    out = xT + (long)b * 131072;
    R_in = 256; rs_in = 512; Rpad = 256; tiles_r = 4;
  }
  const int tr = zt % tiles_r, tc = zt / tiles_r;
  const int r0 = tr * 64, c0 = tc * 64;
  const int c = threadIdx.x & 63, l0 = threadIdx.x >> 6;

#pragma unroll 4
  for (int i = 0; i < 16; ++i) {
    int l = l0 + i * 4;
    int gr = r0 + l;
    float v = 0.f;
    if (gr < R_in) v = in[(long)gr * rs_in + c0 + c];
    tile[l][c] = v;
  }
  __syncthreads();
#pragma unroll 4
  for (int i = 0; i < 16; ++i) {
    int cr = l0 + i * 4;
    out[(long)(c0 + cr) * Rpad + r0 + c] = f2bf(tile[c][cr]);
  }
}

// ---------------------------------------------------------------------------
template<int RAW>
__global__ __launch_bounds__(256)
void ln_k(const float* __restrict__ in, const float* __restrict__ g,
          const float* __restrict__ b, short* __restrict__ outp,
          short* __restrict__ rawp, int rows)
{
  int row = blockIdx.x * 4 + (threadIdx.x >> 6);
  if (row >= rows) return;
  int lane = threadIdx.x & 63;
  const float* p = in + (long)row * 512 + lane * 8;
  f32x4 v0 = *(const f32x4*)p, v1 = *(const f32x4*)(p + 4);
  if constexpr (RAW) {
    short* rp = rawp + (long)row * 512 + lane * 8;
    *(s16x8*)rp = cvt8(v0, v1);
  }
  float s = 0.f, sq = 0.f;
#pragma unroll
  for (int j = 0; j < 4; ++j) { s += v0[j] + v1[j]; sq += v0[j]*v0[j] + v1[j]*v1[j]; }
#pragma unroll
  for (int o = 1; o < 64; o <<= 1) { s += __shfl_xor(s, o); sq += __shfl_xor(sq, o); }
  float mean = s * (1.f / 512.f);
  float var  = sq * (1.f / 512.f) - mean * mean;
  float rs   = rsqrtf(var + 1e-6f);
  const f32x4 g0 = *(const f32x4*)(g + lane * 8), g1 = *(const f32x4*)(g + lane * 8 + 4);
  const f32x4 b0 = *(const f32x4*)(b + lane * 8), b1 = *(const f32x4*)(b + lane * 8 + 4);
  f32x4 o0, o1;
#pragma unroll
  for (int j = 0; j < 4; ++j) {
    o0[j] = g0[j] * (v0[j] - mean) * rs + b0[j];
    o1[j] = g1[j] * (v1[j] - mean) * rs + b1[j];
  }
  short* op = outp + (long)row * 512 + lane * 8;
  *(s16x8*)op = cvt8(o0, o1);
}

// ---------------------------------------------------------------------------
static GemmP mkP(const short* A, int hbA, long sAo, long sAi, int lda,
                 const short* B, int hbB, long sBo, long sBi, int ldb,
                 void* C, int hbC, long sCo, long sCi, int ldc,
                 const float* bias, const float* r1, const float* r2,
                 int M, int N, int K, float alpha, int nvalid)
{
  GemmP P;
  P.A = A; P.hbA = hbA; P.sAo = sAo; P.sAi = sAi; P.lda = lda;
  P.B = B; P.hbB = hbB; P.sBo = sBo; P.sBi = sBi; P.ldb = ldb;
  P.C = C; P.hbC = hbC; P.sCo = sCo; P.sCi = sCi; P.ldc = ldc;
  P.bias = bias; P.res1 = r1; P.res2 = r2;
  P.M = M; P.N = N; P.K = K; P.alpha = alpha; P.nvalid = nvalid;
  return P;
}

extern "C" void kernel_launch(void* const* d_in, const int* in_sizes, int n_in,
                              void* d_out, int out_size, void* d_ws, size_t ws_size,
                              hipStream_t stream)
{
  (void)in_sizes; (void)n_in; (void)out_size; (void)ws_size;

  const float* x     = (const float*)d_in[0];
  const float* text  = (const float*)d_in[1];
  const float* vis   = (const float*)d_in[2];
  const float* ftw   = (const float*)d_in[3];
  const float* ftb   = (const float*)d_in[4];
  const float* ftw1  = (const float*)d_in[5];
  const float* ftb1  = (const float*)d_in[6];
  const float* ftw2  = (const float*)d_in[7];
  const float* ftb2  = (const float*)d_in[8];
  const float* ftln  = (const float*)d_in[9];
  const float* fvw   = (const float*)d_in[10];
  const float* fvb   = (const float*)d_in[11];
  const float* fvw1  = (const float*)d_in[12];
  const float* fvb1  = (const float*)d_in[13];
  const float* fvw2  = (const float*)d_in[14];
  const float* fvb2  = (const float*)d_in[15];
  const float* fvln  = (const float*)d_in[16];
  const float* ldmln = (const float*)d_in[17];
  const float* afw   = (const float*)d_in[18];
  const float* afb   = (const float*)d_in[19];
  float* out = (float*)d_out;

  char* ws = (char*)d_ws;
  short* wT     = (short*)ws;
  short* xbf    = (short*)(ws + 14680064);
  short* bufLN  = (short*)(ws + 23068672);
  short* bufQ   = (short*)(ws + 29491200);
  short* bufKV  = (short*)(ws + 37879808);
  short* bufT   = (short*)(ws + 54657024);
  short* bufS   = (short*)(ws + 63045632);
  short* bufO   = (short*)(ws + 88735744);
  float* bufX1  = (float*)(ws + 97124352);
  float* bufA2  = (float*)(ws + 109969408);
  short* bufMED = (short*)(ws + 122814464);
  short* bufT2  = (short*)(ws + 129236992);   // x^T, 8,388,608 B
  short* textbf = bufO;
  short* visbf  = (short*)bufA2;
  short* bufSD  = bufS + 2097152;             // D-scores region

  short* ftWq  = wT + 0;
  short* ftWk  = wT + 262144;
  short* ftWv  = wT + 524288;
  short* ftWo  = wT + 786432;
  short* ftW1t = wT + 1048576;
  short* ftW2t = wT + 2097152;
  short* fvWq  = wT + 3145728;
  short* fvWk  = wT + 3407872;
  short* fvWv  = wT + 3670016;
  short* fvWo  = wT + 3932160;
  short* fvW1t = wT + 4194304;
  short* fvW2t = wT + 5242880;
  short* afW00 = wT + 6291456;
  short* afW01 = wT + 6553600;
  short* afW10 = wT + 6815744;
  short* afW11 = wT + 7077888;

  const float AFS = 0.04419417382415922f;
  dim3 blk(256);

  // ---- prep: single merged dispatch (weights + converts + x^T) ----
  prep_k<<<dim3(256, 64), blk, 0, stream>>>(
      ftw, fvw, afw, ftw1, fvw1, ftw2, fvw2, x, text,
      wT, ftW1t, ftW2t, xbf, textbf, bufT2);

  // ================= Phase A: cross_layer(vis, text, ft) =================
  ln_k<1><<<1568, blk, 0, stream>>>(vis, ftln + 0, ftln + 512, bufLN, visbf, 6272);
  // merged Q-proj + K-proj
  gemm2_k<0,128,64,2,2,3,0,0,0,0,1><<<dim3(113,8,1), blk, 0, stream>>>(
      mkP(bufLN,1,0,0,512, ftWq,1,0,0,512, bufQ,1,0,0,512,
          ftb + 0, nullptr, nullptr, 6272,512,512, 1.f, 0),
      mkP(textbf,1,0,0,512, ftWk,1,0,0,512, bufKV,1,0,0,512,
          ftb + 512, nullptr, nullptr, 8192,512,512, 1.f, 0), 49);
  gemm_k<0,128,64,2,2,3,0,0,0,1,2><<<dim3(4,4,32), blk, 0, stream>>>(
      mkP(ftWv,1,0,0,512, textbf,1,131072L,0L,512, bufT,1,131072L,0L,256,
          ftb + 1024, nullptr, nullptr, 512,256,512, 1.f, 0));
  mha_k<<<dim3(4,1,256), blk, 0, stream>>>(bufQ, 100352L, bufKV, 131072L, 512, 256,
      bufT, 16384L, bufO, 196, 0.125f, 256);
  gemm_k<1,128,64,2,2,3,0,0,1,0,1><<<dim3(49,8,1), blk, 0, stream>>>(
      mkP(bufO,1,0,0,512, ftWo,1,0,0,512, bufX1,1,0,0,512,
          ftb + 1536, vis, nullptr, 6272,512,512, 1.f, 0));
  ln_k<0><<<1568, blk, 0, stream>>>(bufX1, ftln + 1024, ftln + 1536, bufLN, nullptr, 6272);
  gemm_k<0,128,128,2,2,2,0,1,0,0,1><<<dim3(49,16,1), blk, 0, stream>>>(
      mkP(bufLN,1,0,0,512, ftW1t,1,0,0,512, bufS,1,0,0,2048,
          ftb1, nullptr, nullptr, 6272,2048,512, 1.f, 0));
  gemm_k<1,128,64,2,2,3,0,0,1,0,1><<<dim3(49,8,1), blk, 0, stream>>>(
      mkP(bufS,1,0,0,2048, ftW2t,1,0,0,2048, bufX1,1,0,0,512,
          ftb2, bufX1, nullptr, 6272,512,2048, 1.f, 0));

  // ================= Phase B: cross_layer(med1, vis, fv) + med1 =================
  ln_k<0><<<1568, blk, 0, stream>>>(bufX1, fvln + 0, fvln + 512, bufLN, nullptr, 6272);
  gemm2_k<0,128,64,2,2,3,0,0,0,0,1><<<dim3(98,8,1), blk, 0, stream>>>(
      mkP(bufLN,1,0,0,512, fvWq,1,0,0,512, bufQ,1,0,0,512,
          fvb + 0, nullptr, nullptr, 6272,512,512, 1.f, 0),
      mkP(visbf,1,0,0,512, fvWk,1,0,0,512, bufKV,1,0,0,512,
          fvb + 512, nullptr, nullptr, 6272,512,512, 1.f, 0), 49);
  gemm_k<0,128,64,2,2,3,0,0,0,1,2><<<dim3(4,4,32), blk, 0, stream>>>(
      mkP(fvWv,1,0,0,512, visbf,1,100352L,0L,512, bufT,1,131072L,0L,256,
          fvb + 1024, nullptr, nullptr, 512,196,512, 1.f, 0));
  mha_k<<<dim3(4,1,256), blk, 0, stream>>>(bufQ, 100352L, bufKV, 100352L, 512, 196,
      bufT, 16384L, bufO, 196, 0.125f, 196);
  gemm_k<1,128,64,2,2,3,0,0,1,0,1><<<dim3(49,8,1), blk, 0, stream>>>(
      mkP(bufO,1,0,0,512, fvWo,1,0,0,512, bufA2,1,0,0,512,
          fvb + 1536, bufX1, nullptr, 6272,512,512, 1.f, 0));
  ln_k<0><<<1568, blk, 0, stream>>>(bufA2, fvln + 1024, fvln + 1536, bufLN, nullptr, 6272);
  gemm_k<0,128,128,2,2,2,0,1,0,0,1><<<dim3(49,16,1), blk, 0, stream>>>(
      mkP(bufLN,1,0,0,512, fvW1t,1,0,0,512, bufS,1,0,0,2048,
          fvb1, nullptr, nullptr, 6272,2048,512, 1.f, 0));
  gemm_k<1,128,64,2,2,3,0,0,2,0,1><<<dim3(49,8,1), blk, 0, stream>>>(
      mkP(bufS,1,0,0,2048, fvW2t,1,0,0,2048, bufA2,1,0,0,512,
          fvb2, bufA2, bufX1, 6272,512,2048, 1.f, 0));
  ln_k<0><<<1568, blk, 0, stream>>>(bufA2, ldmln + 0, ldmln + 512, bufMED, nullptr, 6272);

  // ============ Phases C+D interleaved: v_af then out ============
  gemm2_k<0,128,64,2,2,3,0,0,0,0,1><<<dim3(113,8,1), blk, 0, stream>>>(
      mkP(bufMED,1,0,0,512, afW00,1,0,0,512, bufQ,1,0,0,512,
          afb + 0, nullptr, nullptr, 6272,512,512, 1.f, 0),
      mkP(xbf,1,0,0,512, afW10,1,0,0,512, bufKV,1,0,0,512,
          afb + 1024, nullptr, nullptr, 8192,512,512, 1.f, 0), 49);
  gemm2_k<0,32,256,2,1,2,1,0,0,0,2><<<dim3(15,1,32), dim3(128), 0, stream>>>(
      mkP(bufQ,1,100352L,0L,512, xbf,1,131072L,0L,512, bufS,1,50176L,0L,256,
          nullptr, nullptr, nullptr, 196,256,512, AFS, 256),
      mkP(bufKV,1,131072L,0L,512, bufMED,1,100352L,0L,512, bufSD,1,65536L,0L,256,
          nullptr, nullptr, nullptr, 256,256,512, AFS, 196), 7);
  gemm_k<0,64,128,2,2,3,0,0,0,0,2><<<dim3(4,4,32), blk, 0, stream>>>(
      mkP(bufS,1,50176L,0L,256, bufT2,1,131072L,0L,256, bufO,1,100352L,0L,512,
          nullptr, nullptr, nullptr, 196,512,256, 1.f, 0));
  gemm_k<0,128,64,2,2,3,0,0,0,1,2><<<dim3(4,4,32), blk, 0, stream>>>(
      mkP(afW01,1,0,0,512, bufO,1,100352L,0L,512, bufT,1,131072L,0L,256,
          afb + 512, nullptr, nullptr, 512,256,512, 1.f, 0));
  gemm_k<0,64,128,2,2,3,0,0,0,0,2><<<dim3(4,4,32), blk, 0, stream>>>(
      mkP(bufSD,1,65536L,0L,256, bufT,1,131072L,0L,256, bufO,1,131072L,0L,512,
          nullptr, nullptr, nullptr, 256,512,256, 1.f, 0));
  gemm_k<1,128,64,2,2,3,0,0,1,0,1><<<dim3(64,8,1), blk, 0, stream>>>(
      mkP(bufO,1,0,0,512, afW11,1,0,0,512, out,1,0,0,512,
          afb + 1536, x, nullptr, 8192,512,512, 1.f, 0));
}

// Round 17
// 333.513 us; speedup vs baseline: 1.0296x; 1.0149x over previous
//
#include <hip/hip_runtime.h>
#include <hip/hip_bf16.h>

typedef __attribute__((ext_vector_type(4))) float f32x4;
typedef __attribute__((ext_vector_type(8))) short s16x8;
typedef __attribute__((ext_vector_type(4))) short s16x4;

__device__ __forceinline__ short f2bf(float f) {
  union { float f; unsigned u; } c; c.f = f;
  unsigned r = c.u + 0x7fffu + ((c.u >> 16) & 1u);
  return (short)(r >> 16);
}
__device__ __forceinline__ float bf2f(short h) {
  union { unsigned u; float f; } c; c.u = ((unsigned)(unsigned short)h) << 16;
  return c.f;
}
__device__ __forceinline__ s16x8 cvt8(const f32x4& lo, const f32x4& hi) {
  s16x8 v;
  v[0] = f2bf(lo[0]); v[1] = f2bf(lo[1]); v[2] = f2bf(lo[2]); v[3] = f2bf(lo[3]);
  v[4] = f2bf(hi[0]); v[5] = f2bf(hi[1]); v[6] = f2bf(hi[2]); v[7] = f2bf(hi[3]);
  return v;
}

__device__ __forceinline__ void gl_lds16(const short* g, char* l) {
  __builtin_amdgcn_global_load_lds(
      (const __attribute__((address_space(1))) unsigned int*)g,
      (__attribute__((address_space(3))) unsigned int*)l, 16, 0, 0);
}

// ---------------------------------------------------------------------------
// Runtime parameter pack for one GEMM problem
// ---------------------------------------------------------------------------
struct GemmP {
  const short* A; int hbA; long sAo, sAi; int lda;
  const short* B; int hbB; long sBo, sBi; int ldb;
  void* C; int hbC; long sCo, sCi; int ldc;
  const float* bias; const float* res1; const float* res2;
  int M, N, K; float alpha; int nvalid;
};

// ---------------------------------------------------------------------------
// GEMM body (all-bf16 in): C = alpha*A[M,K]@B[N,K]^T (+bias/res/softmax)
// ---------------------------------------------------------------------------
template<int CF32, int BM, int BN, int WRN, int WCN, int RING,
         int SM, int RELU, int NRES, int BIASM>
__device__ __forceinline__
void gemm_body(const GemmP& P, int bx, int by, int bz)
{
  constexpr int WAVES = WRN * WCN;
  constexpr int T = WAVES * 64;
  constexpr int MI = BM / (WRN * 16), NI = BN / (WCN * 16);
  constexpr int ACH = BM * 8 / T, BCH = BN * 8 / T;
  constexpr int L   = ACH + BCH;
  constexpr int ABYTES = BM * 128;
  constexpr int TBYTES = (BM + BN) * 128;
  constexpr int LSTR = BN + (CF32 ? 4 : 8);
  constexpr int EPIB = BM * LSTR * (CF32 ? 4 : 2);
  constexpr int SMEMB = (RING * TBYTES > EPIB) ? RING * TBYTES : EPIB;
  __shared__ __align__(16) char smem[SMEMB];

  const int tid  = threadIdx.x;
  const int lane = tid & 63;
  const int wid  = tid >> 6;
  const int wr   = wid / WCN, wc = wid % WCN;

  const int m0 = bx * BM, n0 = by * BN;
  const int z  = bz;

  const int zA = z / P.hbA, zAi = z - zA * P.hbA;
  const int zB = z / P.hbB, zBi = z - zB * P.hbB;
  const int zC = z / P.hbC, zCi = z - zC * P.hbC;
  const short* Ab = P.A + (long)zA * P.sAo + (long)zAi * P.sAi;
  const short* Bb = P.B + (long)zB * P.sBo + (long)zBi * P.sBi;
  char*        Cb = (char*)P.C + ((long)zC * P.sCo + (long)zCi * P.sCi) * (CF32 ? 4 : 2);

  int aL[ACH]; long aG[ACH];
#pragma unroll
  for (int j = 0; j < ACH; ++j) {
    int chunk = (j * WAVES + wid) * 64 + lane;
    int row = chunk >> 3;
    int c   = (chunk & 7) ^ (row & 7);
    int gr = m0 + row; if (gr > P.M - 1) gr = P.M - 1;
    aL[j] = chunk * 16;
    aG[j] = (long)gr * P.lda + c * 8;
  }
  int bL[BCH]; long bG[BCH];
#pragma unroll
  for (int j = 0; j < BCH; ++j) {
    int chunk = (j * WAVES + wid) * 64 + lane;
    int row = chunk >> 3;
    int c   = (chunk & 7) ^ (row & 7);
    int gc = n0 + row; if (gc > P.N - 1) gc = P.N - 1;
    bL[j] = chunk * 16;
    bG[j] = (long)gc * P.ldb + c * 8;
  }

  auto stage = [&](int buf, int kt) {
    const short* Akt = Ab + (long)kt * 64;
    char* base = smem + buf * TBYTES;
#pragma unroll
    for (int j = 0; j < ACH; ++j) gl_lds16(Akt + aG[j], base + aL[j]);
    const short* Bkt = Bb + (long)kt * 64;
#pragma unroll
    for (int j = 0; j < BCH; ++j) gl_lds16(Bkt + bG[j], base + ABYTES + bL[j]);
  };

  int ard[2][MI], brd[2][NI];
#pragma unroll
  for (int kk = 0; kk < 2; ++kk) {
    int kgr = kk * 4 + (lane >> 4);
#pragma unroll
    for (int mi = 0; mi < MI; ++mi) {
      int m = wr * (BM / WRN) + mi * 16 + (lane & 15);
      ard[kk][mi] = m * 128 + ((kgr ^ (m & 7)) << 4);
    }
#pragma unroll
    for (int ni = 0; ni < NI; ++ni) {
      int n = wc * (BN / WCN) + ni * 16 + (lane & 15);
      brd[kk][ni] = ABYTES + n * 128 + ((kgr ^ (n & 7)) << 4);
    }
  }

  const int NT = P.K >> 6;
#pragma unroll
  for (int p = 0; p < RING; ++p) if (p < NT) stage(p, p);

  f32x4 acc[MI][NI];
#pragma unroll
  for (int mi = 0; mi < MI; ++mi)
#pragma unroll
    for (int ni = 0; ni < NI; ++ni) acc[mi][ni] = (f32x4){0.f, 0.f, 0.f, 0.f};

  int bufi = 0;
  for (int t = 0; t < NT; ++t) {
    const int rem = NT - t;
    if constexpr (RING == 3) {
      if (rem >= 3)      asm volatile("s_waitcnt vmcnt(%0)" :: "n"(2 * L) : "memory");
      else if (rem == 2) asm volatile("s_waitcnt vmcnt(%0)" :: "n"(L) : "memory");
      else               asm volatile("s_waitcnt vmcnt(0)" ::: "memory");
    } else if constexpr (RING == 2) {
      if (rem >= 2)      asm volatile("s_waitcnt vmcnt(%0)" :: "n"(L) : "memory");
      else               asm volatile("s_waitcnt vmcnt(0)" ::: "memory");
    } else {
      asm volatile("s_waitcnt vmcnt(0)" ::: "memory");
    }
    asm volatile("s_barrier" ::: "memory");

    const char* base = smem + bufi * TBYTES;
#pragma unroll
    for (int kk = 0; kk < 2; ++kk) {
      s16x8 af[MI];
#pragma unroll
      for (int mi = 0; mi < MI; ++mi) af[mi] = *(const s16x8*)(base + ard[kk][mi]);
#pragma unroll
      for (int ni = 0; ni < NI; ++ni) {
        s16x8 bf = *(const s16x8*)(base + brd[kk][ni]);
#pragma unroll
        for (int mi = 0; mi < MI; ++mi)
          acc[mi][ni] = __builtin_amdgcn_mfma_f32_16x16x32_bf16(af[mi], bf, acc[mi][ni], 0, 0, 0);
      }
    }

    if (t + RING < NT) {
      asm volatile("s_waitcnt lgkmcnt(0)" ::: "memory");
      asm volatile("s_barrier" ::: "memory");
      stage(bufi, t + RING);
    }
    bufi = (bufi + 1 == RING) ? 0 : bufi + 1;
  }

  if constexpr (SM) {
#pragma unroll
    for (int mi = 0; mi < MI; ++mi) {
#pragma unroll
      for (int j = 0; j < 4; ++j) {
        float mx = -3.0e38f;
#pragma unroll
        for (int ni = 0; ni < NI; ++ni) {
          int col = n0 + wc * (BN / WCN) + ni * 16 + (lane & 15);
          float s = acc[mi][ni][j] * P.alpha;
          acc[mi][ni][j] = (col < P.nvalid) ? s : -3.0e38f;
          mx = fmaxf(mx, acc[mi][ni][j]);
        }
#pragma unroll
        for (int o = 1; o < 16; o <<= 1) mx = fmaxf(mx, __shfl_xor(mx, o));
        float sum = 0.f;
#pragma unroll
        for (int ni = 0; ni < NI; ++ni) {
          int col = n0 + wc * (BN / WCN) + ni * 16 + (lane & 15);
          float e = (col < P.nvalid) ? __expf(acc[mi][ni][j] - mx) : 0.f;
          acc[mi][ni][j] = e;
          sum += e;
        }
#pragma unroll
        for (int o = 1; o < 16; o <<= 1) sum += __shfl_xor(sum, o);
        float inv = 1.f / sum;
#pragma unroll
        for (int ni = 0; ni < NI; ++ni) acc[mi][ni][j] *= inv;
      }
    }
  }
  const float aep = SM ? 1.f : P.alpha;

  asm volatile("s_waitcnt lgkmcnt(0)" ::: "memory");
  __syncthreads();

  {
    float* lf = (float*)smem;
    short* lh = (short*)smem;
#pragma unroll
    for (int mi = 0; mi < MI; ++mi)
#pragma unroll
      for (int ni = 0; ni < NI; ++ni) {
        int c_loc = wc * (BN / WCN) + ni * 16 + (lane & 15);
        float bv = (P.bias && !BIASM) ? P.bias[n0 + c_loc] : 0.f;
        int rb = wr * (BM / WRN) + mi * 16 + ((lane >> 4) << 2);
#pragma unroll
        for (int j = 0; j < 4; ++j) {
          float v = acc[mi][ni][j] * aep + bv;
          if constexpr (CF32) lf[(rb + j) * LSTR + c_loc] = v;
          else                lh[(rb + j) * LSTR + c_loc] = f2bf(v);
        }
      }
  }
  __syncthreads();

  constexpr int CPR = BN / 8;
  constexpr int RP  = T / CPR;
  const int rr0 = tid / CPR;
  const int cc  = (tid % CPR) * 8;
  for (int r = rr0; r < BM; r += RP) {
    const int gr = m0 + r;
    if (gr >= P.M) break;
    f32x4 a, b;
    if constexpr (CF32) {
      a = *(const f32x4*)((const float*)smem + (long)r * LSTR + cc);
      b = *(const f32x4*)((const float*)smem + (long)r * LSTR + cc + 4);
    } else {
      s16x8 h = *(const s16x8*)((const short*)smem + (long)r * LSTR + cc);
#pragma unroll
      for (int j = 0; j < 4; ++j) { a[j] = bf2f(h[j]); b[j] = bf2f(h[j + 4]); }
    }
    if constexpr (BIASM) {
      float bm = P.bias[gr];
#pragma unroll
      for (int j = 0; j < 4; ++j) { a[j] += bm; b[j] += bm; }
    }
    const long gb = (long)gr * P.ldc + n0 + cc;
    if constexpr (NRES >= 1) {
      f32x4 r1 = *(const f32x4*)(P.res1 + gb), r2 = *(const f32x4*)(P.res1 + gb + 4);
#pragma unroll
      for (int j = 0; j < 4; ++j) { a[j] += r1[j]; b[j] += r2[j]; }
    }
    if constexpr (NRES >= 2) {
      f32x4 r1 = *(const f32x4*)(P.res2 + gb), r2 = *(const f32x4*)(P.res2 + gb + 4);
#pragma unroll
      for (int j = 0; j < 4; ++j) { a[j] += r1[j]; b[j] += r2[j]; }
    }
    if constexpr (RELU) {
#pragma unroll
      for (int j = 0; j < 4; ++j) { a[j] = fmaxf(a[j], 0.f); b[j] = fmaxf(b[j], 0.f); }
    }
    if constexpr (CF32) {
      *(f32x4*)((float*)Cb + gb) = a;
      *(f32x4*)((float*)Cb + gb + 4) = b;
    } else {
      *(s16x8*)((short*)Cb + gb) = cvt8(a, b);
    }
  }
}

// XCD-chunked bijective remap over a linear id
__device__ __forceinline__ int xcd_remap(int o, int nwg)
{
  const int q = nwg >> 3, r = nwg & 7;
  const int xcd = o & 7, slot = o >> 3;
  return (xcd < r ? xcd * (q + 1) : r * (q + 1) + (xcd - r) * q) + slot;
}

// ---------------------------------------------------------------------------
// Single-problem GEMM kernel
// ---------------------------------------------------------------------------
template<int CF32, int BM, int BN, int WRN, int WCN, int RING,
         int SM, int RELU, int NRES, int BIASM, int SWZ>
__global__ __launch_bounds__(WRN * WCN * 64, 2)
void gemm_k(GemmP P)
{
  int bx = blockIdx.x, by = blockIdx.y, bz = blockIdx.z;
  if constexpr (SWZ == 1) {
    const int gx = gridDim.x, gy = gridDim.y;
    const int w = xcd_remap(by * gx + bx, gx * gy);
    bx = w / gy; by = w - bx * gy;
  } else if constexpr (SWZ == 2) {
    const int gx = gridDim.x, gy = gridDim.y, gz = gridDim.z;
    int w = xcd_remap((bz * gy + by) * gx + bx, gx * gy * gz);
    bx = w % gx; w /= gx; by = w % gy; bz = w / gy;
  }
  gemm_body<CF32, BM, BN, WRN, WCN, RING, SM, RELU, NRES, BIASM>(P, bx, by, bz);
}

// ---------------------------------------------------------------------------
// Dual-problem GEMM kernel: blocks with remapped bx < split run p0, else p1.
// ---------------------------------------------------------------------------
template<int CF32, int BM, int BN, int WRN, int WCN, int RING,
         int SM, int RELU, int NRES, int BIASM, int SWZ>
__global__ __launch_bounds__(WRN * WCN * 64, 2)
void gemm2_k(GemmP p0, GemmP p1, int split)
{
  int bx = blockIdx.x, by = blockIdx.y, bz = blockIdx.z;
  if constexpr (SWZ == 1) {
    const int gx = gridDim.x, gy = gridDim.y;
    const int w = xcd_remap(by * gx + bx, gx * gy);
    bx = w / gy; by = w - bx * gy;
  } else if constexpr (SWZ == 2) {
    const int gx = gridDim.x, gy = gridDim.y, gz = gridDim.z;
    int w = xcd_remap((bz * gy + by) * gx + bx, gx * gy * gz);
    bx = w % gx; w /= gx; by = w % gy; bz = w / gy;
  }
  const bool first = (bx < split);
  const GemmP& P = first ? p0 : p1;
  if (!first) bx -= split;
  gemm_body<CF32, BM, BN, WRN, WCN, RING, SM, RELU, NRES, BIASM>(P, bx, by, bz);
}

// ---------------------------------------------------------------------------
// Fused MHA with XCD-chunked block remap
// ---------------------------------------------------------------------------
__global__ __launch_bounds__(256, 2)
void mha_k(const short* __restrict__ Qp, long qStride,
           const short* __restrict__ Kp, long kStride, int ldk, int Lkv,
           const short* __restrict__ VTp, long vtStride,
           short* __restrict__ Op, int Lq, float alpha, int nvalid)
{
  __shared__ __align__(16) char smem[73728];
  char* Qs  = smem;
  char* Ks  = smem + 8192;
  char* VTs = smem + 40960;

  const int tid = threadIdx.x, lane = tid & 63, wid = tid >> 6;

  int bxr = blockIdx.x, bzr = blockIdx.z;
  {
    const int gx = gridDim.x, gz = gridDim.z;
    int w = xcd_remap(bzr * gx + bxr, gx * gz);
    bxr = w % gx; bzr = w / gx;
  }
  const int z = bzr, b = z >> 3, h = z & 7;
  const int m0 = bxr * 64;

  const short* Qb  = Qp + (long)b * qStride + h * 64;
  const short* Kb  = Kp + (long)b * kStride + h * 64;
  const short* VTb = VTp + (long)z * vtStride;
  short*       Ob  = Op + (long)b * qStride + h * 64;

#pragma unroll
  for (int j = 0; j < 2; ++j) {
    int chunk = (j * 4 + wid) * 64 + lane;
    int row = chunk >> 3, c = (chunk & 7) ^ (row & 7);
    int gr = m0 + row; if (gr > Lq - 1) gr = Lq - 1;
    gl_lds16(Qb + (long)gr * 512 + c * 8, Qs + chunk * 16);
  }
#pragma unroll
  for (int j = 0; j < 8; ++j) {
    int chunk = (j * 4 + wid) * 64 + lane;
    int row = chunk >> 3, c = (chunk & 7) ^ (row & 7);
    int gr = row; if (gr > Lkv - 1) gr = Lkv - 1;
    gl_lds16(Kb + (long)gr * ldk + c * 8, Ks + chunk * 16);
  }
#pragma unroll
  for (int j = 0; j < 8; ++j) {
    int chunk = (j * 4 + wid) * 64 + lane;
    int row = chunk >> 5, cw = (chunk & 31) ^ (row & 15);
    gl_lds16(VTb + (long)row * 256 + cw * 8, VTs + chunk * 16);
  }
  __syncthreads();

  f32x4 acc[16];
#pragma unroll
  for (int ni = 0; ni < 16; ++ni) acc[ni] = (f32x4){0.f, 0.f, 0.f, 0.f};
#pragma unroll
  for (int kk = 0; kk < 2; ++kk) {
    int kgr = kk * 4 + (lane >> 4);
    int m = wid * 16 + (lane & 15);
    s16x8 af = *(const s16x8*)(Qs + m * 128 + ((kgr ^ (m & 7)) << 4));
#pragma unroll
    for (int ni = 0; ni < 16; ++ni) {
      int n = ni * 16 + (lane & 15);
      s16x8 bf = *(const s16x8*)(Ks + n * 128 + ((kgr ^ (n & 7)) << 4));
      acc[ni] = __builtin_amdgcn_mfma_f32_16x16x32_bf16(af, bf, acc[ni], 0, 0, 0);
    }
  }

#pragma unroll
  for (int j = 0; j < 4; ++j) {
    float mx = -3.0e38f;
#pragma unroll
    for (int ni = 0; ni < 16; ++ni) {
      int col = ni * 16 + (lane & 15);
      float s = acc[ni][j] * alpha;
      acc[ni][j] = (col < nvalid) ? s : -3.0e38f;
      mx = fmaxf(mx, acc[ni][j]);
    }
#pragma unroll
    for (int o = 1; o < 16; o <<= 1) mx = fmaxf(mx, __shfl_xor(mx, o));
    float sum = 0.f;
#pragma unroll
    for (int ni = 0; ni < 16; ++ni) {
      int col = ni * 16 + (lane & 15);
      float e = (col < nvalid) ? __expf(acc[ni][j] - mx) : 0.f;
      acc[ni][j] = e;
      sum += e;
    }
#pragma unroll
    for (int o = 1; o < 16; o <<= 1) sum += __shfl_xor(sum, o);
    float inv = 1.f / sum;
#pragma unroll
    for (int ni = 0; ni < 16; ++ni) acc[ni][j] *= inv;
  }

  __syncthreads();

  {
    char* Ps = Ks + wid * 8192;
    const int r0 = (lane >> 4) * 4;
#pragma unroll
    for (int ni = 0; ni < 16; ++ni) {
      int col = ni * 16 + (lane & 15);
      int chunk = col >> 3, cin = (col & 7) * 2;
#pragma unroll
      for (int j = 0; j < 4; ++j) {
        int row = r0 + j;
        *(short*)(Ps + row * 512 + ((chunk ^ (row & 15)) << 4) + cin) = f2bf(acc[ni][j]);
      }
    }
  }
  asm volatile("s_waitcnt lgkmcnt(0)" ::: "memory");

  f32x4 acco[4];
#pragma unroll
  for (int ni = 0; ni < 4; ++ni) acco[ni] = (f32x4){0.f, 0.f, 0.f, 0.f};
  {
    const char* Ps = Ks + wid * 8192;
#pragma unroll
    for (int kk = 0; kk < 8; ++kk) {
      int g = lane >> 4;
      int mrow = lane & 15;
      int achunk = (kk * 4 + g) ^ (mrow & 15);
      s16x8 af = *(const s16x8*)(Ps + mrow * 512 + (achunk << 4));
#pragma unroll
      for (int ni = 0; ni < 4; ++ni) {
        int n = ni * 16 + (lane & 15);
        int bchunk = (kk * 4 + g) ^ (n & 15);
        s16x8 bf = *(const s16x8*)(VTs + n * 512 + (bchunk << 4));
        acco[ni] = __builtin_amdgcn_mfma_f32_16x16x32_bf16(af, bf, acco[ni], 0, 0, 0);
      }
    }
  }

  __syncthreads();

  {
    short* lh = (short*)smem;
#pragma unroll
    for (int ni = 0; ni < 4; ++ni) {
      int d = ni * 16 + (lane & 15);
      int rb = wid * 16 + ((lane >> 4) << 2);
#pragma unroll
      for (int j = 0; j < 4; ++j) lh[(rb + j) * 72 + d] = f2bf(acco[ni][j]);
    }
  }
  __syncthreads();
  {
    const int r0 = tid >> 3, cc = (tid & 7) * 8;
#pragma unroll
    for (int p = 0; p < 2; ++p) {
      int r = r0 + p * 32;
      int gr = m0 + r;
      if (gr < Lq) {
        s16x8 h8 = *(const s16x8*)((const short*)smem + r * 72 + cc);
        *(s16x8*)(Ob + (long)gr * 512 + cc) = h8;
      }
    }
  }
}

// ---------------------------------------------------------------------------
// Merged prep: weight transposes (z<16), x/text fp32->bf16 (z 16-31),
// x^T per-batch transpose (z 32-63). One dispatch.
// ---------------------------------------------------------------------------
__global__ __launch_bounds__(256)
void prep_k(const float* ftw, const float* fvw, const float* afw,
            const float* ftw1, const float* fvw1,
            const float* ftw2, const float* fvw2,
            const float* x, const float* text,
            short* wTbase, short* dW1, short* dW2,
            short* xbf, short* textbf, short* xT)
{
  const int z = blockIdx.y, zt = blockIdx.x;

  if (z >= 16 && z < 32) {
    long off = (long)(z & 7) * 524288 + (long)zt * 2048 + threadIdx.x * 8;
    const float* src = (z < 24 ? x : text) + off;
    short* dst = (z < 24 ? xbf : textbf) + off;
    f32x4 lo = *(const f32x4*)src, hi = *(const f32x4*)(src + 4);
    *(s16x8*)dst = cvt8(lo, hi);
    return;
  }

  __shared__ float tile[64][65];
  const float* in; short* out;
  int R_in, rs_in, Rpad, tiles_r;
  if (z < 12) {
    if (zt >= 64) return;
    const int grp = z >> 2, idx = z & 3;
    in = (grp == 0 ? ftw : grp == 1 ? fvw : afw) + (long)idx * 262144;
    out = wTbase + (long)grp * 3145728 + (long)idx * 262144;
    R_in = 512; rs_in = 512; Rpad = 512; tiles_r = 8;
  } else if (z < 14) {
    const int idx = z - 12;
    in = (idx == 0 ? ftw1 : fvw1);
    out = (idx == 0 ? dW1 : dW1 + 3145728);
    R_in = 512; rs_in = 2048; Rpad = 512; tiles_r = 8;
  } else if (z < 16) {
    const int idx = z - 14;
    in = (idx == 0 ? ftw2 : fvw2);
    out = (idx == 0 ? dW2 : dW2 + 3145728);
    R_in = 2048; rs_in = 512; Rpad = 2048; tiles_r = 32;
  } else {
    if (zt >= 32) return;
    const int b = z - 32;
    in = x + (long)b * 131072;
    out = xT + (long)b * 131072;
    R_in = 256; rs_in = 512; Rpad = 256; tiles_r = 4;
  }
  const int tr = zt % tiles_r, tc = zt / tiles_r;
  const int r0 = tr * 64, c0 = tc * 64;
  const int c = threadIdx.x & 63, l0 = threadIdx.x >> 6;

#pragma unroll 4
  for (int i = 0; i < 16; ++i) {
    int l = l0 + i * 4;
    int gr = r0 + l;
    float v = 0.f;
    if (gr < R_in) v = in[(long)gr * rs_in + c0 + c];
    tile[l][c] = v;
  }
  __syncthreads();
#pragma unroll 4
  for (int i = 0; i < 16; ++i) {
    int cr = l0 + i * 4;
    out[(long)(c0 + cr) * Rpad + r0 + c] = f2bf(tile[c][cr]);
  }
}

// ---------------------------------------------------------------------------
template<int RAW>
__global__ __launch_bounds__(256)
void ln_k(const float* __restrict__ in, const float* __restrict__ g,
          const float* __restrict__ b, short* __restrict__ outp,
          short* __restrict__ rawp, int rows)
{
  int row = blockIdx.x * 4 + (threadIdx.x >> 6);
  if (row >= rows) return;
  int lane = threadIdx.x & 63;
  const float* p = in + (long)row * 512 + lane * 8;
  f32x4 v0 = *(const f32x4*)p, v1 = *(const f32x4*)(p + 4);
  if constexpr (RAW) {
    short* rp = rawp + (long)row * 512 + lane * 8;
    *(s16x8*)rp = cvt8(v0, v1);
  }
  float s = 0.f, sq = 0.f;
#pragma unroll
  for (int j = 0; j < 4; ++j) { s += v0[j] + v1[j]; sq += v0[j]*v0[j] + v1[j]*v1[j]; }
#pragma unroll
  for (int o = 1; o < 64; o <<= 1) { s += __shfl_xor(s, o); sq += __shfl_xor(sq, o); }
  float mean = s * (1.f / 512.f);
  float var  = sq * (1.f / 512.f) - mean * mean;
  float rs   = rsqrtf(var + 1e-6f);
  const f32x4 g0 = *(const f32x4*)(g + lane * 8), g1 = *(const f32x4*)(g + lane * 8 + 4);
  const f32x4 b0 = *(const f32x4*)(b + lane * 8), b1 = *(const f32x4*)(b + lane * 8 + 4);
  f32x4 o0, o1;
#pragma unroll
  for (int j = 0; j < 4; ++j) {
    o0[j] = g0[j] * (v0[j] - mean) * rs + b0[j];
    o1[j] = g1[j] * (v1[j] - mean) * rs + b1[j];
  }
  short* op = outp + (long)row * 512 + lane * 8;
  *(s16x8*)op = cvt8(o0, o1);
}

// ---------------------------------------------------------------------------
static GemmP mkP(const short* A, int hbA, long sAo, long sAi, int lda,
                 const short* B, int hbB, long sBo, long sBi, int ldb,
                 void* C, int hbC, long sCo, long sCi, int ldc,
                 const float* bias, const float* r1, const float* r2,
                 int M, int N, int K, float alpha, int nvalid)
{
  GemmP P;
  P.A = A; P.hbA = hbA; P.sAo = sAo; P.sAi = sAi; P.lda = lda;
  P.B = B; P.hbB = hbB; P.sBo = sBo; P.sBi = sBi; P.ldb = ldb;
  P.C = C; P.hbC = hbC; P.sCo = sCo; P.sCi = sCi; P.ldc = ldc;
  P.bias = bias; P.res1 = r1; P.res2 = r2;
  P.M = M; P.N = N; P.K = K; P.alpha = alpha; P.nvalid = nvalid;
  return P;
}

extern "C" void kernel_launch(void* const* d_in, const int* in_sizes, int n_in,
                              void* d_out, int out_size, void* d_ws, size_t ws_size,
                              hipStream_t stream)
{
  (void)in_sizes; (void)n_in; (void)out_size; (void)ws_size;

  const float* x     = (const float*)d_in[0];
  const float* text  = (const float*)d_in[1];
  const float* vis   = (const float*)d_in[2];
  const float* ftw   = (const float*)d_in[3];
  const float* ftb   = (const float*)d_in[4];
  const float* ftw1  = (const float*)d_in[5];
  const float* ftb1  = (const float*)d_in[6];
  const float* ftw2  = (const float*)d_in[7];
  const float* ftb2  = (const float*)d_in[8];
  const float* ftln  = (const float*)d_in[9];
  const float* fvw   = (const float*)d_in[10];
  const float* fvb   = (const float*)d_in[11];
  const float* fvw1  = (const float*)d_in[12];
  const float* fvb1  = (const float*)d_in[13];
  const float* fvw2  = (const float*)d_in[14];
  const float* fvb2  = (const float*)d_in[15];
  const float* fvln  = (const float*)d_in[16];
  const float* ldmln = (const float*)d_in[17];
  const float* afw   = (const float*)d_in[18];
  const float* afb   = (const float*)d_in[19];
  float* out = (float*)d_out;

  char* ws = (char*)d_ws;
  short* wT     = (short*)ws;
  short* xbf    = (short*)(ws + 14680064);
  short* bufLN  = (short*)(ws + 23068672);
  short* bufQ   = (short*)(ws + 29491200);
  short* bufKV  = (short*)(ws + 37879808);
  short* bufT   = (short*)(ws + 54657024);
  short* bufS   = (short*)(ws + 63045632);
  short* bufO   = (short*)(ws + 88735744);
  float* bufX1  = (float*)(ws + 97124352);
  float* bufA2  = (float*)(ws + 109969408);
  short* bufMED = (short*)(ws + 122814464);
  short* bufT2  = (short*)(ws + 129236992);   // x^T, 8,388,608 B
  short* textbf = bufO;
  short* visbf  = (short*)bufA2;
  short* bufSD  = bufS + 2097152;             // D-scores region

  short* ftWq  = wT + 0;
  short* ftWk  = wT + 262144;
  short* ftWv  = wT + 524288;
  short* ftWo  = wT + 786432;
  short* ftW1t = wT + 1048576;
  short* ftW2t = wT + 2097152;
  short* fvWq  = wT + 3145728;
  short* fvWk  = wT + 3407872;
  short* fvWv  = wT + 3670016;
  short* fvWo  = wT + 3932160;
  short* fvW1t = wT + 4194304;
  short* fvW2t = wT + 5242880;
  short* afW00 = wT + 6291456;
  short* afW01 = wT + 6553600;
  short* afW10 = wT + 6815744;
  short* afW11 = wT + 7077888;

  const float AFS = 0.04419417382415922f;
  dim3 blk(256);

  // ---- prep: single merged dispatch (weights + converts + x^T) ----
  prep_k<<<dim3(256, 64), blk, 0, stream>>>(
      ftw, fvw, afw, ftw1, fvw1, ftw2, fvw2, x, text,
      wT, ftW1t, ftW2t, xbf, textbf, bufT2);

  // ================= Phase A: cross_layer(vis, text, ft) =================
  ln_k<1><<<1568, blk, 0, stream>>>(vis, ftln + 0, ftln + 512, bufLN, visbf, 6272);
  // merged Q-proj + K-proj  (RING=2: 48KB LDS -> 3 blocks/CU)
  gemm2_k<0,128,64,2,2,2,0,0,0,0,1><<<dim3(113,8,1), blk, 0, stream>>>(
      mkP(bufLN,1,0,0,512, ftWq,1,0,0,512, bufQ,1,0,0,512,
          ftb + 0, nullptr, nullptr, 6272,512,512, 1.f, 0),
      mkP(textbf,1,0,0,512, ftWk,1,0,0,512, bufKV,1,0,0,512,
          ftb + 512, nullptr, nullptr, 8192,512,512, 1.f, 0), 49);
  gemm_k<0,128,64,2,2,2,0,0,0,1,2><<<dim3(4,4,32), blk, 0, stream>>>(
      mkP(ftWv,1,0,0,512, textbf,1,131072L,0L,512, bufT,1,131072L,0L,256,
          ftb + 1024, nullptr, nullptr, 512,256,512, 1.f, 0));
  mha_k<<<dim3(4,1,256), blk, 0, stream>>>(bufQ, 100352L, bufKV, 131072L, 512, 256,
      bufT, 16384L, bufO, 196, 0.125f, 256);
  gemm_k<1,128,64,2,2,2,0,0,1,0,1><<<dim3(49,8,1), blk, 0, stream>>>(
      mkP(bufO,1,0,0,512, ftWo,1,0,0,512, bufX1,1,0,0,512,
          ftb + 1536, vis, nullptr, 6272,512,512, 1.f, 0));
  ln_k<0><<<1568, blk, 0, stream>>>(bufX1, ftln + 1024, ftln + 1536, bufLN, nullptr, 6272);
  gemm_k<0,128,128,2,2,2,0,1,0,0,1><<<dim3(49,16,1), blk, 0, stream>>>(
      mkP(bufLN,1,0,0,512, ftW1t,1,0,0,512, bufS,1,0,0,2048,
          ftb1, nullptr, nullptr, 6272,2048,512, 1.f, 0));
  gemm_k<1,128,64,2,2,3,0,0,1,0,1><<<dim3(49,8,1), blk, 0, stream>>>(
      mkP(bufS,1,0,0,2048, ftW2t,1,0,0,2048, bufX1,1,0,0,512,
          ftb2, bufX1, nullptr, 6272,512,2048, 1.f, 0));

  // ================= Phase B: cross_layer(med1, vis, fv) + med1 =================
  ln_k<0><<<1568, blk, 0, stream>>>(bufX1, fvln + 0, fvln + 512, bufLN, nullptr, 6272);
  gemm2_k<0,128,64,2,2,2,0,0,0,0,1><<<dim3(98,8,1), blk, 0, stream>>>(
      mkP(bufLN,1,0,0,512, fvWq,1,0,0,512, bufQ,1,0,0,512,
          fvb + 0, nullptr, nullptr, 6272,512,512, 1.f, 0),
      mkP(visbf,1,0,0,512, fvWk,1,0,0,512, bufKV,1,0,0,512,
          fvb + 512, nullptr, nullptr, 6272,512,512, 1.f, 0), 49);
  gemm_k<0,128,64,2,2,2,0,0,0,1,2><<<dim3(4,4,32), blk, 0, stream>>>(
      mkP(fvWv,1,0,0,512, visbf,1,100352L,0L,512, bufT,1,131072L,0L,256,
          fvb + 1024, nullptr, nullptr, 512,196,512, 1.f, 0));
  mha_k<<<dim3(4,1,256), blk, 0, stream>>>(bufQ, 100352L, bufKV, 100352L, 512, 196,
      bufT, 16384L, bufO, 196, 0.125f, 196);
  gemm_k<1,128,64,2,2,2,0,0,1,0,1><<<dim3(49,8,1), blk, 0, stream>>>(
      mkP(bufO,1,0,0,512, fvWo,1,0,0,512, bufA2,1,0,0,512,
          fvb + 1536, bufX1, nullptr, 6272,512,512, 1.f, 0));
  ln_k<0><<<1568, blk, 0, stream>>>(bufA2, fvln + 1024, fvln + 1536, bufLN, nullptr, 6272);
  gemm_k<0,128,128,2,2,2,0,1,0,0,1><<<dim3(49,16,1), blk, 0, stream>>>(
      mkP(bufLN,1,0,0,512, fvW1t,1,0,0,512, bufS,1,0,0,2048,
          fvb1, nullptr, nullptr, 6272,2048,512, 1.f, 0));
  gemm_k<1,128,64,2,2,3,0,0,2,0,1><<<dim3(49,8,1), blk, 0, stream>>>(
      mkP(bufS,1,0,0,2048, fvW2t,1,0,0,2048, bufA2,1,0,0,512,
          fvb2, bufA2, bufX1, 6272,512,2048, 1.f, 0));
  ln_k<0><<<1568, blk, 0, stream>>>(bufA2, ldmln + 0, ldmln + 512, bufMED, nullptr, 6272);

  // ============ Phases C+D interleaved: v_af then out ============
  gemm2_k<0,128,64,2,2,2,0,0,0,0,1><<<dim3(113,8,1), blk, 0, stream>>>(
      mkP(bufMED,1,0,0,512, afW00,1,0,0,512, bufQ,1,0,0,512,
          afb + 0, nullptr, nullptr, 6272,512,512, 1.f, 0),
      mkP(xbf,1,0,0,512, afW10,1,0,0,512, bufKV,1,0,0,512,
          afb + 1024, nullptr, nullptr, 8192,512,512, 1.f, 0), 49);
  gemm2_k<0,32,256,2,1,2,1,0,0,0,2><<<dim3(15,1,32), dim3(128), 0, stream>>>(
      mkP(bufQ,1,100352L,0L,512, xbf,1,131072L,0L,512, bufS,1,50176L,0L,256,
          nullptr, nullptr, nullptr, 196,256,512, AFS, 256),
      mkP(bufKV,1,131072L,0L,512, bufMED,1,100352L,0L,512, bufSD,1,65536L,0L,256,
          nullptr, nullptr, nullptr, 256,256,512, AFS, 196), 7);
  gemm_k<0,64,128,2,2,2,0,0,0,0,2><<<dim3(4,4,32), blk, 0, stream>>>(
      mkP(bufS,1,50176L,0L,256, bufT2,1,131072L,0L,256, bufO,1,100352L,0L,512,
          nullptr, nullptr, nullptr, 196,512,256, 1.f, 0));
  gemm_k<0,128,64,2,2,2,0,0,0,1,2><<<dim3(4,4,32), blk, 0, stream>>>(
      mkP(afW01,1,0,0,512, bufO,1,100352L,0L,512, bufT,1,131072L,0L,256,
          afb + 512, nullptr, nullptr, 512,256,512, 1.f, 0));
  gemm_k<0,64,128,2,2,2,0,0,0,0,2><<<dim3(4,4,32), blk, 0, stream>>>(
      mkP(bufSD,1,65536L,0L,256, bufT,1,131072L,0L,256, bufO,1,131072L,0L,512,
          nullptr, nullptr, nullptr, 256,512,256, 1.f, 0));
  gemm_k<1,128,64,2,2,2,0,0,1,0,1><<<dim3(64,8,1), blk, 0, stream>>>(
      mkP(bufO,1,0,0,512, afW11,1,0,0,512, out,1,0,0,512,
          afb + 1536, x, nullptr, 8192,512,512, 1.f, 0));
}

// Round 18
// 331.386 us; speedup vs baseline: 1.0362x; 1.0064x over previous
//
#include <hip/hip_runtime.h>
#include <hip/hip_bf16.h>

typedef __attribute__((ext_vector_type(4))) float f32x4;
typedef __attribute__((ext_vector_type(8))) short s16x8;
typedef __attribute__((ext_vector_type(4))) short s16x4;

__device__ __forceinline__ short f2bf(float f) {
  union { float f; unsigned u; } c; c.f = f;
  unsigned r = c.u + 0x7fffu + ((c.u >> 16) & 1u);
  return (short)(r >> 16);
}
__device__ __forceinline__ float bf2f(short h) {
  union { unsigned u; float f; } c; c.u = ((unsigned)(unsigned short)h) << 16;
  return c.f;
}
__device__ __forceinline__ s16x8 cvt8(const f32x4& lo, const f32x4& hi) {
  s16x8 v;
  v[0] = f2bf(lo[0]); v[1] = f2bf(lo[1]); v[2] = f2bf(lo[2]); v[3] = f2bf(lo[3]);
  v[4] = f2bf(hi[0]); v[5] = f2bf(hi[1]); v[6] = f2bf(hi[2]); v[7] = f2bf(hi[3]);
  return v;
}

__device__ __forceinline__ void gl_lds16(const short* g, char* l) {
  __builtin_amdgcn_global_load_lds(
      (const __attribute__((address_space(1))) unsigned int*)g,
      (__attribute__((address_space(3))) unsigned int*)l, 16, 0, 0);
}

// ---------------------------------------------------------------------------
// Runtime parameter pack for one GEMM problem
// ---------------------------------------------------------------------------
struct GemmP {
  const short* A; int hbA; long sAo, sAi; int lda;
  const short* B; int hbB; long sBo, sBi; int ldb;
  void* C; int hbC; long sCo, sCi; int ldc;
  const float* bias; const float* res1; const float* res2;
  int M, N, K; float alpha; int nvalid;
};

// ---------------------------------------------------------------------------
// GEMM body (all-bf16 in): C = alpha*A[M,K]@B[N,K]^T (+bias/res/softmax)
// ---------------------------------------------------------------------------
template<int CF32, int BM, int BN, int WRN, int WCN, int RING,
         int SM, int RELU, int NRES, int BIASM>
__device__ __forceinline__
void gemm_body(const GemmP& P, int bx, int by, int bz)
{
  constexpr int WAVES = WRN * WCN;
  constexpr int T = WAVES * 64;
  constexpr int MI = BM / (WRN * 16), NI = BN / (WCN * 16);
  constexpr int ACH = BM * 8 / T, BCH = BN * 8 / T;
  constexpr int L   = ACH + BCH;
  constexpr int ABYTES = BM * 128;
  constexpr int TBYTES = (BM + BN) * 128;
  constexpr int LSTR = BN + (CF32 ? 4 : 8);
  constexpr int EPIB = BM * LSTR * (CF32 ? 4 : 2);
  constexpr int SMEMB = (RING * TBYTES > EPIB) ? RING * TBYTES : EPIB;
  __shared__ __align__(16) char smem[SMEMB];

  const int tid  = threadIdx.x;
  const int lane = tid & 63;
  const int wid  = tid >> 6;
  const int wr   = wid / WCN, wc = wid % WCN;

  const int m0 = bx * BM, n0 = by * BN;
  const int z  = bz;

  const int zA = z / P.hbA, zAi = z - zA * P.hbA;
  const int zB = z / P.hbB, zBi = z - zB * P.hbB;
  const int zC = z / P.hbC, zCi = z - zC * P.hbC;
  const short* Ab = P.A + (long)zA * P.sAo + (long)zAi * P.sAi;
  const short* Bb = P.B + (long)zB * P.sBo + (long)zBi * P.sBi;
  char*        Cb = (char*)P.C + ((long)zC * P.sCo + (long)zCi * P.sCi) * (CF32 ? 4 : 2);

  int aL[ACH]; long aG[ACH];
#pragma unroll
  for (int j = 0; j < ACH; ++j) {
    int chunk = (j * WAVES + wid) * 64 + lane;
    int row = chunk >> 3;
    int c   = (chunk & 7) ^ (row & 7);
    int gr = m0 + row; if (gr > P.M - 1) gr = P.M - 1;
    aL[j] = chunk * 16;
    aG[j] = (long)gr * P.lda + c * 8;
  }
  int bL[BCH]; long bG[BCH];
#pragma unroll
  for (int j = 0; j < BCH; ++j) {
    int chunk = (j * WAVES + wid) * 64 + lane;
    int row = chunk >> 3;
    int c   = (chunk & 7) ^ (row & 7);
    int gc = n0 + row; if (gc > P.N - 1) gc = P.N - 1;
    bL[j] = chunk * 16;
    bG[j] = (long)gc * P.ldb + c * 8;
  }

  auto stage = [&](int buf, int kt) {
    const short* Akt = Ab + (long)kt * 64;
    char* base = smem + buf * TBYTES;
#pragma unroll
    for (int j = 0; j < ACH; ++j) gl_lds16(Akt + aG[j], base + aL[j]);
    const short* Bkt = Bb + (long)kt * 64;
#pragma unroll
    for (int j = 0; j < BCH; ++j) gl_lds16(Bkt + bG[j], base + ABYTES + bL[j]);
  };

  int ard[2][MI], brd[2][NI];
#pragma unroll
  for (int kk = 0; kk < 2; ++kk) {
    int kgr = kk * 4 + (lane >> 4);
#pragma unroll
    for (int mi = 0; mi < MI; ++mi) {
      int m = wr * (BM / WRN) + mi * 16 + (lane & 15);
      ard[kk][mi] = m * 128 + ((kgr ^ (m & 7)) << 4);
    }
#pragma unroll
    for (int ni = 0; ni < NI; ++ni) {
      int n = wc * (BN / WCN) + ni * 16 + (lane & 15);
      brd[kk][ni] = ABYTES + n * 128 + ((kgr ^ (n & 7)) << 4);
    }
  }

  const int NT = P.K >> 6;
#pragma unroll
  for (int p = 0; p < RING; ++p) if (p < NT) stage(p, p);

  f32x4 acc[MI][NI];
#pragma unroll
  for (int mi = 0; mi < MI; ++mi)
#pragma unroll
    for (int ni = 0; ni < NI; ++ni) acc[mi][ni] = (f32x4){0.f, 0.f, 0.f, 0.f};

  int bufi = 0;
  for (int t = 0; t < NT; ++t) {
    const int rem = NT - t;
    if constexpr (RING == 3) {
      if (rem >= 3)      asm volatile("s_waitcnt vmcnt(%0)" :: "n"(2 * L) : "memory");
      else if (rem == 2) asm volatile("s_waitcnt vmcnt(%0)" :: "n"(L) : "memory");
      else               asm volatile("s_waitcnt vmcnt(0)" ::: "memory");
    } else if constexpr (RING == 2) {
      if (rem >= 2)      asm volatile("s_waitcnt vmcnt(%0)" :: "n"(L) : "memory");
      else               asm volatile("s_waitcnt vmcnt(0)" ::: "memory");
    } else {
      asm volatile("s_waitcnt vmcnt(0)" ::: "memory");
    }
    asm volatile("s_barrier" ::: "memory");

    const char* base = smem + bufi * TBYTES;
#pragma unroll
    for (int kk = 0; kk < 2; ++kk) {
      s16x8 af[MI];
#pragma unroll
      for (int mi = 0; mi < MI; ++mi) af[mi] = *(const s16x8*)(base + ard[kk][mi]);
#pragma unroll
      for (int ni = 0; ni < NI; ++ni) {
        s16x8 bf = *(const s16x8*)(base + brd[kk][ni]);
#pragma unroll
        for (int mi = 0; mi < MI; ++mi)
          acc[mi][ni] = __builtin_amdgcn_mfma_f32_16x16x32_bf16(af[mi], bf, acc[mi][ni], 0, 0, 0);
      }
    }

    if (t + RING < NT) {
      asm volatile("s_waitcnt lgkmcnt(0)" ::: "memory");
      asm volatile("s_barrier" ::: "memory");
      stage(bufi, t + RING);
    }
    bufi = (bufi + 1 == RING) ? 0 : bufi + 1;
  }

  if constexpr (SM) {
#pragma unroll
    for (int mi = 0; mi < MI; ++mi) {
#pragma unroll
      for (int j = 0; j < 4; ++j) {
        float mx = -3.0e38f;
#pragma unroll
        for (int ni = 0; ni < NI; ++ni) {
          int col = n0 + wc * (BN / WCN) + ni * 16 + (lane & 15);
          float s = acc[mi][ni][j] * P.alpha;
          acc[mi][ni][j] = (col < P.nvalid) ? s : -3.0e38f;
          mx = fmaxf(mx, acc[mi][ni][j]);
        }
#pragma unroll
        for (int o = 1; o < 16; o <<= 1) mx = fmaxf(mx, __shfl_xor(mx, o));
        float sum = 0.f;
#pragma unroll
        for (int ni = 0; ni < NI; ++ni) {
          int col = n0 + wc * (BN / WCN) + ni * 16 + (lane & 15);
          float e = (col < P.nvalid) ? __expf(acc[mi][ni][j] - mx) : 0.f;
          acc[mi][ni][j] = e;
          sum += e;
        }
#pragma unroll
        for (int o = 1; o < 16; o <<= 1) sum += __shfl_xor(sum, o);
        float inv = 1.f / sum;
#pragma unroll
        for (int ni = 0; ni < NI; ++ni) acc[mi][ni][j] *= inv;
      }
    }
  }
  const float aep = SM ? 1.f : P.alpha;

  asm volatile("s_waitcnt lgkmcnt(0)" ::: "memory");
  __syncthreads();

  {
    float* lf = (float*)smem;
    short* lh = (short*)smem;
#pragma unroll
    for (int mi = 0; mi < MI; ++mi)
#pragma unroll
      for (int ni = 0; ni < NI; ++ni) {
        int c_loc = wc * (BN / WCN) + ni * 16 + (lane & 15);
        float bv = (P.bias && !BIASM) ? P.bias[n0 + c_loc] : 0.f;
        int rb = wr * (BM / WRN) + mi * 16 + ((lane >> 4) << 2);
#pragma unroll
        for (int j = 0; j < 4; ++j) {
          float v = acc[mi][ni][j] * aep + bv;
          if constexpr (CF32) lf[(rb + j) * LSTR + c_loc] = v;
          else                lh[(rb + j) * LSTR + c_loc] = f2bf(v);
        }
      }
  }
  __syncthreads();

  constexpr int CPR = BN / 8;
  constexpr int RP  = T / CPR;
  const int rr0 = tid / CPR;
  const int cc  = (tid % CPR) * 8;
  for (int r = rr0; r < BM; r += RP) {
    const int gr = m0 + r;
    if (gr >= P.M) break;
    f32x4 a, b;
    if constexpr (CF32) {
      a = *(const f32x4*)((const float*)smem + (long)r * LSTR + cc);
      b = *(const f32x4*)((const float*)smem + (long)r * LSTR + cc + 4);
    } else {
      s16x8 h = *(const s16x8*)((const short*)smem + (long)r * LSTR + cc);
#pragma unroll
      for (int j = 0; j < 4; ++j) { a[j] = bf2f(h[j]); b[j] = bf2f(h[j + 4]); }
    }
    if constexpr (BIASM) {
      float bm = P.bias[gr];
#pragma unroll
      for (int j = 0; j < 4; ++j) { a[j] += bm; b[j] += bm; }
    }
    const long gb = (long)gr * P.ldc + n0 + cc;
    if constexpr (NRES >= 1) {
      f32x4 r1 = *(const f32x4*)(P.res1 + gb), r2 = *(const f32x4*)(P.res1 + gb + 4);
#pragma unroll
      for (int j = 0; j < 4; ++j) { a[j] += r1[j]; b[j] += r2[j]; }
    }
    if constexpr (NRES >= 2) {
      f32x4 r1 = *(const f32x4*)(P.res2 + gb), r2 = *(const f32x4*)(P.res2 + gb + 4);
#pragma unroll
      for (int j = 0; j < 4; ++j) { a[j] += r1[j]; b[j] += r2[j]; }
    }
    if constexpr (RELU) {
#pragma unroll
      for (int j = 0; j < 4; ++j) { a[j] = fmaxf(a[j], 0.f); b[j] = fmaxf(b[j], 0.f); }
    }
    if constexpr (CF32) {
      *(f32x4*)((float*)Cb + gb) = a;
      *(f32x4*)((float*)Cb + gb + 4) = b;
    } else {
      *(s16x8*)((short*)Cb + gb) = cvt8(a, b);
    }
  }
}

// XCD-chunked bijective remap over a linear id
__device__ __forceinline__ int xcd_remap(int o, int nwg)
{
  const int q = nwg >> 3, r = nwg & 7;
  const int xcd = o & 7, slot = o >> 3;
  return (xcd < r ? xcd * (q + 1) : r * (q + 1) + (xcd - r) * q) + slot;
}

// ---------------------------------------------------------------------------
// Single-problem GEMM kernel
// ---------------------------------------------------------------------------
template<int CF32, int BM, int BN, int WRN, int WCN, int RING,
         int SM, int RELU, int NRES, int BIASM, int SWZ>
__global__ __launch_bounds__(WRN * WCN * 64, 2)
void gemm_k(GemmP P)
{
  int bx = blockIdx.x, by = blockIdx.y, bz = blockIdx.z;
  if constexpr (SWZ == 1) {
    const int gx = gridDim.x, gy = gridDim.y;
    const int w = xcd_remap(by * gx + bx, gx * gy);
    bx = w / gy; by = w - bx * gy;
  } else if constexpr (SWZ == 2) {
    const int gx = gridDim.x, gy = gridDim.y, gz = gridDim.z;
    int w = xcd_remap((bz * gy + by) * gx + bx, gx * gy * gz);
    bx = w % gx; w /= gx; by = w % gy; bz = w / gy;
  }
  gemm_body<CF32, BM, BN, WRN, WCN, RING, SM, RELU, NRES, BIASM>(P, bx, by, bz);
}

// ---------------------------------------------------------------------------
// Dual-problem GEMM kernel: blocks with remapped bx < split run p0, else p1.
// ---------------------------------------------------------------------------
template<int CF32, int BM, int BN, int WRN, int WCN, int RING,
         int SM, int RELU, int NRES, int BIASM, int SWZ>
__global__ __launch_bounds__(WRN * WCN * 64, 2)
void gemm2_k(GemmP p0, GemmP p1, int split)
{
  int bx = blockIdx.x, by = blockIdx.y, bz = blockIdx.z;
  if constexpr (SWZ == 1) {
    const int gx = gridDim.x, gy = gridDim.y;
    const int w = xcd_remap(by * gx + bx, gx * gy);
    bx = w / gy; by = w - bx * gy;
  } else if constexpr (SWZ == 2) {
    const int gx = gridDim.x, gy = gridDim.y, gz = gridDim.z;
    int w = xcd_remap((bz * gy + by) * gx + bx, gx * gy * gz);
    bx = w % gx; w /= gx; by = w % gy; bz = w / gy;
  }
  const bool first = (bx < split);
  const GemmP& P = first ? p0 : p1;
  if (!first) bx -= split;
  gemm_body<CF32, BM, BN, WRN, WCN, RING, SM, RELU, NRES, BIASM>(P, bx, by, bz);
}

// ---------------------------------------------------------------------------
// Fused MHA with XCD-chunked block remap
// ---------------------------------------------------------------------------
__global__ __launch_bounds__(256, 2)
void mha_k(const short* __restrict__ Qp, long qStride,
           const short* __restrict__ Kp, long kStride, int ldk, int Lkv,
           const short* __restrict__ VTp, long vtStride,
           short* __restrict__ Op, int Lq, float alpha, int nvalid)
{
  __shared__ __align__(16) char smem[73728];
  char* Qs  = smem;
  char* Ks  = smem + 8192;
  char* VTs = smem + 40960;

  const int tid = threadIdx.x, lane = tid & 63, wid = tid >> 6;

  int bxr = blockIdx.x, bzr = blockIdx.z;
  {
    const int gx = gridDim.x, gz = gridDim.z;
    int w = xcd_remap(bzr * gx + bxr, gx * gz);
    bxr = w % gx; bzr = w / gx;
  }
  const int z = bzr, b = z >> 3, h = z & 7;
  const int m0 = bxr * 64;

  const short* Qb  = Qp + (long)b * qStride + h * 64;
  const short* Kb  = Kp + (long)b * kStride + h * 64;
  const short* VTb = VTp + (long)z * vtStride;
  short*       Ob  = Op + (long)b * qStride + h * 64;

#pragma unroll
  for (int j = 0; j < 2; ++j) {
    int chunk = (j * 4 + wid) * 64 + lane;
    int row = chunk >> 3, c = (chunk & 7) ^ (row & 7);
    int gr = m0 + row; if (gr > Lq - 1) gr = Lq - 1;
    gl_lds16(Qb + (long)gr * 512 + c * 8, Qs + chunk * 16);
  }
#pragma unroll
  for (int j = 0; j < 8; ++j) {
    int chunk = (j * 4 + wid) * 64 + lane;
    int row = chunk >> 3, c = (chunk & 7) ^ (row & 7);
    int gr = row; if (gr > Lkv - 1) gr = Lkv - 1;
    gl_lds16(Kb + (long)gr * ldk + c * 8, Ks + chunk * 16);
  }
#pragma unroll
  for (int j = 0; j < 8; ++j) {
    int chunk = (j * 4 + wid) * 64 + lane;
    int row = chunk >> 5, cw = (chunk & 31) ^ (row & 15);
    gl_lds16(VTb + (long)row * 256 + cw * 8, VTs + chunk * 16);
  }
  __syncthreads();

  f32x4 acc[16];
#pragma unroll
  for (int ni = 0; ni < 16; ++ni) acc[ni] = (f32x4){0.f, 0.f, 0.f, 0.f};
#pragma unroll
  for (int kk = 0; kk < 2; ++kk) {
    int kgr = kk * 4 + (lane >> 4);
    int m = wid * 16 + (lane & 15);
    s16x8 af = *(const s16x8*)(Qs + m * 128 + ((kgr ^ (m & 7)) << 4));
#pragma unroll
    for (int ni = 0; ni < 16; ++ni) {
      int n = ni * 16 + (lane & 15);
      s16x8 bf = *(const s16x8*)(Ks + n * 128 + ((kgr ^ (n & 7)) << 4));
      acc[ni] = __builtin_amdgcn_mfma_f32_16x16x32_bf16(af, bf, acc[ni], 0, 0, 0);
    }
  }

#pragma unroll
  for (int j = 0; j < 4; ++j) {
    float mx = -3.0e38f;
#pragma unroll
    for (int ni = 0; ni < 16; ++ni) {
      int col = ni * 16 + (lane & 15);
      float s = acc[ni][j] * alpha;
      acc[ni][j] = (col < nvalid) ? s : -3.0e38f;
      mx = fmaxf(mx, acc[ni][j]);
    }
#pragma unroll
    for (int o = 1; o < 16; o <<= 1) mx = fmaxf(mx, __shfl_xor(mx, o));
    float sum = 0.f;
#pragma unroll
    for (int ni = 0; ni < 16; ++ni) {
      int col = ni * 16 + (lane & 15);
      float e = (col < nvalid) ? __expf(acc[ni][j] - mx) : 0.f;
      acc[ni][j] = e;
      sum += e;
    }
#pragma unroll
    for (int o = 1; o < 16; o <<= 1) sum += __shfl_xor(sum, o);
    float inv = 1.f / sum;
#pragma unroll
    for (int ni = 0; ni < 16; ++ni) acc[ni][j] *= inv;
  }

  __syncthreads();

  {
    char* Ps = Ks + wid * 8192;
    const int r0 = (lane >> 4) * 4;
#pragma unroll
    for (int ni = 0; ni < 16; ++ni) {
      int col = ni * 16 + (lane & 15);
      int chunk = col >> 3, cin = (col & 7) * 2;
#pragma unroll
      for (int j = 0; j < 4; ++j) {
        int row = r0 + j;
        *(short*)(Ps + row * 512 + ((chunk ^ (row & 15)) << 4) + cin) = f2bf(acc[ni][j]);
      }
    }
  }
  asm volatile("s_waitcnt lgkmcnt(0)" ::: "memory");

  f32x4 acco[4];
#pragma unroll
  for (int ni = 0; ni < 4; ++ni) acco[ni] = (f32x4){0.f, 0.f, 0.f, 0.f};
  {
    const char* Ps = Ks + wid * 8192;
#pragma unroll
    for (int kk = 0; kk < 8; ++kk) {
      int g = lane >> 4;
      int mrow = lane & 15;
      int achunk = (kk * 4 + g) ^ (mrow & 15);
      s16x8 af = *(const s16x8*)(Ps + mrow * 512 + (achunk << 4));
#pragma unroll
      for (int ni = 0; ni < 4; ++ni) {
        int n = ni * 16 + (lane & 15);
        int bchunk = (kk * 4 + g) ^ (n & 15);
        s16x8 bf = *(const s16x8*)(VTs + n * 512 + (bchunk << 4));
        acco[ni] = __builtin_amdgcn_mfma_f32_16x16x32_bf16(af, bf, acco[ni], 0, 0, 0);
      }
    }
  }

  __syncthreads();

  {
    short* lh = (short*)smem;
#pragma unroll
    for (int ni = 0; ni < 4; ++ni) {
      int d = ni * 16 + (lane & 15);
      int rb = wid * 16 + ((lane >> 4) << 2);
#pragma unroll
      for (int j = 0; j < 4; ++j) lh[(rb + j) * 72 + d] = f2bf(acco[ni][j]);
    }
  }
  __syncthreads();
  {
    const int r0 = tid >> 3, cc = (tid & 7) * 8;
#pragma unroll
    for (int p = 0; p < 2; ++p) {
      int r = r0 + p * 32;
      int gr = m0 + r;
      if (gr < Lq) {
        s16x8 h8 = *(const s16x8*)((const short*)smem + r * 72 + cc);
        *(s16x8*)(Ob + (long)gr * 512 + cc) = h8;
      }
    }
  }
}

// ---------------------------------------------------------------------------
// Merged prep: weight transposes (z<16), x/text fp32->bf16 (z 16-31),
// x^T per-batch transpose (z 32-63). One dispatch.
// ---------------------------------------------------------------------------
__global__ __launch_bounds__(256)
void prep_k(const float* ftw, const float* fvw, const float* afw,
            const float* ftw1, const float* fvw1,
            const float* ftw2, const float* fvw2,
            const float* x, const float* text,
            short* wTbase, short* dW1, short* dW2,
            short* xbf, short* textbf, short* xT)
{
  const int z = blockIdx.y, zt = blockIdx.x;

  if (z >= 16 && z < 32) {
    long off = (long)(z & 7) * 524288 + (long)zt * 2048 + threadIdx.x * 8;
    const float* src = (z < 24 ? x : text) + off;
    short* dst = (z < 24 ? xbf : textbf) + off;
    f32x4 lo = *(const f32x4*)src, hi = *(const f32x4*)(src + 4);
    *(s16x8*)dst = cvt8(lo, hi);
    return;
  }

  __shared__ float tile[64][65];
  const float* in; short* out;
  int R_in, rs_in, Rpad, tiles_r;
  if (z < 12) {
    if (zt >= 64) return;
    const int grp = z >> 2, idx = z & 3;
    in = (grp == 0 ? ftw : grp == 1 ? fvw : afw) + (long)idx * 262144;
    out = wTbase + (long)grp * 3145728 + (long)idx * 262144;
    R_in = 512; rs_in = 512; Rpad = 512; tiles_r = 8;
  } else if (z < 14) {
    const int idx = z - 12;
    in = (idx == 0 ? ftw1 : fvw1);
    out = (idx == 0 ? dW1 : dW1 + 3145728);
    R_in = 512; rs_in = 2048; Rpad = 512; tiles_r = 8;
  } else if (z < 16) {
    const int idx = z - 14;
    in = (idx == 0 ? ftw2 : fvw2);
    out = (idx == 0 ? dW2 : dW2 + 3145728);
    R_in = 2048; rs_in = 512; Rpad = 2048; tiles_r = 32;
  } else {
    if (zt >= 32) return;
    const int b = z - 32;
    in = x + (long)b * 131072;
    out = xT + (long)b * 131072;
    R_in = 256; rs_in = 512; Rpad = 256; tiles_r = 4;
  }
  const int tr = zt % tiles_r, tc = zt / tiles_r;
  const int r0 = tr * 64, c0 = tc * 64;
  const int c = threadIdx.x & 63, l0 = threadIdx.x >> 6;

#pragma unroll 4
  for (int i = 0; i < 16; ++i) {
    int l = l0 + i * 4;
    int gr = r0 + l;
    float v = 0.f;
    if (gr < R_in) v = in[(long)gr * rs_in + c0 + c];
    tile[l][c] = v;
  }
  __syncthreads();
#pragma unroll 4
  for (int i = 0; i < 16; ++i) {
    int cr = l0 + i * 4;
    out[(long)(c0 + cr) * Rpad + r0 + c] = f2bf(tile[c][cr]);
  }
}

// ---------------------------------------------------------------------------
template<int RAW>
__global__ __launch_bounds__(256)
void ln_k(const float* __restrict__ in, const float* __restrict__ g,
          const float* __restrict__ b, short* __restrict__ outp,
          short* __restrict__ rawp, int rows)
{
  int row = blockIdx.x * 4 + (threadIdx.x >> 6);
  if (row >= rows) return;
  int lane = threadIdx.x & 63;
  const float* p = in + (long)row * 512 + lane * 8;
  f32x4 v0 = *(const f32x4*)p, v1 = *(const f32x4*)(p + 4);
  if constexpr (RAW) {
    short* rp = rawp + (long)row * 512 + lane * 8;
    *(s16x8*)rp = cvt8(v0, v1);
  }
  float s = 0.f, sq = 0.f;
#pragma unroll
  for (int j = 0; j < 4; ++j) { s += v0[j] + v1[j]; sq += v0[j]*v0[j] + v1[j]*v1[j]; }
#pragma unroll
  for (int o = 1; o < 64; o <<= 1) { s += __shfl_xor(s, o); sq += __shfl_xor(sq, o); }
  float mean = s * (1.f / 512.f);
  float var  = sq * (1.f / 512.f) - mean * mean;
  float rs   = rsqrtf(var + 1e-6f);
  const f32x4 g0 = *(const f32x4*)(g + lane * 8), g1 = *(const f32x4*)(g + lane * 8 + 4);
  const f32x4 b0 = *(const f32x4*)(b + lane * 8), b1 = *(const f32x4*)(b + lane * 8 + 4);
  f32x4 o0, o1;
#pragma unroll
  for (int j = 0; j < 4; ++j) {
    o0[j] = g0[j] * (v0[j] - mean) * rs + b0[j];
    o1[j] = g1[j] * (v1[j] - mean) * rs + b1[j];
  }
  short* op = outp + (long)row * 512 + lane * 8;
  *(s16x8*)op = cvt8(o0, o1);
}

// ---------------------------------------------------------------------------
static GemmP mkP(const short* A, int hbA, long sAo, long sAi, int lda,
                 const short* B, int hbB, long sBo, long sBi, int ldb,
                 void* C, int hbC, long sCo, long sCi, int ldc,
                 const float* bias, const float* r1, const float* r2,
                 int M, int N, int K, float alpha, int nvalid)
{
  GemmP P;
  P.A = A; P.hbA = hbA; P.sAo = sAo; P.sAi = sAi; P.lda = lda;
  P.B = B; P.hbB = hbB; P.sBo = sBo; P.sBi = sBi; P.ldb = ldb;
  P.C = C; P.hbC = hbC; P.sCo = sCo; P.sCi = sCi; P.ldc = ldc;
  P.bias = bias; P.res1 = r1; P.res2 = r2;
  P.M = M; P.N = N; P.K = K; P.alpha = alpha; P.nvalid = nvalid;
  return P;
}

extern "C" void kernel_launch(void* const* d_in, const int* in_sizes, int n_in,
                              void* d_out, int out_size, void* d_ws, size_t ws_size,
                              hipStream_t stream)
{
  (void)in_sizes; (void)n_in; (void)out_size; (void)ws_size;

  const float* x     = (const float*)d_in[0];
  const float* text  = (const float*)d_in[1];
  const float* vis   = (const float*)d_in[2];
  const float* ftw   = (const float*)d_in[3];
  const float* ftb   = (const float*)d_in[4];
  const float* ftw1  = (const float*)d_in[5];
  const float* ftb1  = (const float*)d_in[6];
  const float* ftw2  = (const float*)d_in[7];
  const float* ftb2  = (const float*)d_in[8];
  const float* ftln  = (const float*)d_in[9];
  const float* fvw   = (const float*)d_in[10];
  const float* fvb   = (const float*)d_in[11];
  const float* fvw1  = (const float*)d_in[12];
  const float* fvb1  = (const float*)d_in[13];
  const float* fvw2  = (const float*)d_in[14];
  const float* fvb2  = (const float*)d_in[15];
  const float* fvln  = (const float*)d_in[16];
  const float* ldmln = (const float*)d_in[17];
  const float* afw   = (const float*)d_in[18];
  const float* afb   = (const float*)d_in[19];
  float* out = (float*)d_out;

  char* ws = (char*)d_ws;
  short* wT     = (short*)ws;
  short* xbf    = (short*)(ws + 14680064);
  short* bufLN  = (short*)(ws + 23068672);
  short* bufQ   = (short*)(ws + 29491200);
  short* bufKV  = (short*)(ws + 37879808);
  short* bufT   = (short*)(ws + 54657024);
  short* bufS   = (short*)(ws + 63045632);
  short* bufO   = (short*)(ws + 88735744);
  float* bufX1  = (float*)(ws + 97124352);
  float* bufA2  = (float*)(ws + 109969408);
  short* bufMED = (short*)(ws + 122814464);
  short* bufT2  = (short*)(ws + 129236992);   // x^T, 8,388,608 B
  short* textbf = bufO;
  short* visbf  = (short*)bufA2;
  short* bufSD  = bufS + 2097152;             // D-scores region

  short* ftWq  = wT + 0;
  short* ftWk  = wT + 262144;
  short* ftWv  = wT + 524288;
  short* ftWo  = wT + 786432;
  short* ftW1t = wT + 1048576;
  short* ftW2t = wT + 2097152;
  short* fvWq  = wT + 3145728;
  short* fvWk  = wT + 3407872;
  short* fvWv  = wT + 3670016;
  short* fvWo  = wT + 3932160;
  short* fvW1t = wT + 4194304;
  short* fvW2t = wT + 5242880;
  short* afW00 = wT + 6291456;
  short* afW01 = wT + 6553600;
  short* afW10 = wT + 6815744;
  short* afW11 = wT + 7077888;

  const float AFS = 0.04419417382415922f;
  dim3 blk(256);

  // ---- prep: single merged dispatch (weights + converts + x^T) ----
  prep_k<<<dim3(256, 64), blk, 0, stream>>>(
      ftw, fvw, afw, ftw1, fvw1, ftw2, fvw2, x, text,
      wT, ftW1t, ftW2t, xbf, textbf, bufT2);

  // ================= Phase A: cross_layer(vis, text, ft) =================
  ln_k<1><<<1568, blk, 0, stream>>>(vis, ftln + 0, ftln + 512, bufLN, visbf, 6272);
  // merged Q-proj + K-proj  (RING=2: 48KB LDS -> 3 blocks/CU)
  gemm2_k<0,128,64,2,2,2,0,0,0,0,1><<<dim3(113,8,1), blk, 0, stream>>>(
      mkP(bufLN,1,0,0,512, ftWq,1,0,0,512, bufQ,1,0,0,512,
          ftb + 0, nullptr, nullptr, 6272,512,512, 1.f, 0),
      mkP(textbf,1,0,0,512, ftWk,1,0,0,512, bufKV,1,0,0,512,
          ftb + 512, nullptr, nullptr, 8192,512,512, 1.f, 0), 49);
  gemm_k<0,128,64,2,2,2,0,0,0,1,2><<<dim3(4,4,32), blk, 0, stream>>>(
      mkP(ftWv,1,0,0,512, textbf,1,131072L,0L,512, bufT,1,131072L,0L,256,
          ftb + 1024, nullptr, nullptr, 512,256,512, 1.f, 0));
  mha_k<<<dim3(4,1,256), blk, 0, stream>>>(bufQ, 100352L, bufKV, 131072L, 512, 256,
      bufT, 16384L, bufO, 196, 0.125f, 256);
  gemm_k<1,128,64,2,2,2,0,0,1,0,1><<<dim3(49,8,1), blk, 0, stream>>>(
      mkP(bufO,1,0,0,512, ftWo,1,0,0,512, bufX1,1,0,0,512,
          ftb + 1536, vis, nullptr, 6272,512,512, 1.f, 0));
  ln_k<0><<<1568, blk, 0, stream>>>(bufX1, ftln + 1024, ftln + 1536, bufLN, nullptr, 6272);
  gemm_k<0,128,128,2,2,2,0,1,0,0,1><<<dim3(49,16,1), blk, 0, stream>>>(
      mkP(bufLN,1,0,0,512, ftW1t,1,0,0,512, bufS,1,0,0,2048,
          ftb1, nullptr, nullptr, 6272,2048,512, 1.f, 0));
  gemm_k<1,128,64,2,2,2,0,0,1,0,1><<<dim3(49,8,1), blk, 0, stream>>>(
      mkP(bufS,1,0,0,2048, ftW2t,1,0,0,2048, bufX1,1,0,0,512,
          ftb2, bufX1, nullptr, 6272,512,2048, 1.f, 0));

  // ================= Phase B: cross_layer(med1, vis, fv) + med1 =================
  ln_k<0><<<1568, blk, 0, stream>>>(bufX1, fvln + 0, fvln + 512, bufLN, nullptr, 6272);
  gemm2_k<0,128,64,2,2,2,0,0,0,0,1><<<dim3(98,8,1), blk, 0, stream>>>(
      mkP(bufLN,1,0,0,512, fvWq,1,0,0,512, bufQ,1,0,0,512,
          fvb + 0, nullptr, nullptr, 6272,512,512, 1.f, 0),
      mkP(visbf,1,0,0,512, fvWk,1,0,0,512, bufKV,1,0,0,512,
          fvb + 512, nullptr, nullptr, 6272,512,512, 1.f, 0), 49);
  gemm_k<0,128,64,2,2,2,0,0,0,1,2><<<dim3(4,4,32), blk, 0, stream>>>(
      mkP(fvWv,1,0,0,512, visbf,1,100352L,0L,512, bufT,1,131072L,0L,256,
          fvb + 1024, nullptr, nullptr, 512,196,512, 1.f, 0));
  mha_k<<<dim3(4,1,256), blk, 0, stream>>>(bufQ, 100352L, bufKV, 100352L, 512, 196,
      bufT, 16384L, bufO, 196, 0.125f, 196);
  gemm_k<1,128,64,2,2,2,0,0,1,0,1><<<dim3(49,8,1), blk, 0, stream>>>(
      mkP(bufO,1,0,0,512, fvWo,1,0,0,512, bufA2,1,0,0,512,
          fvb + 1536, bufX1, nullptr, 6272,512,512, 1.f, 0));
  ln_k<0><<<1568, blk, 0, stream>>>(bufA2, fvln + 1024, fvln + 1536, bufLN, nullptr, 6272);
  gemm_k<0,128,128,2,2,2,0,1,0,0,1><<<dim3(49,16,1), blk, 0, stream>>>(
      mkP(bufLN,1,0,0,512, fvW1t,1,0,0,512, bufS,1,0,0,2048,
          fvb1, nullptr, nullptr, 6272,2048,512, 1.f, 0));
  gemm_k<1,128,64,2,2,2,0,0,2,0,1><<<dim3(49,8,1), blk, 0, stream>>>(
      mkP(bufS,1,0,0,2048, fvW2t,1,0,0,2048, bufA2,1,0,0,512,
          fvb2, bufA2, bufX1, 6272,512,2048, 1.f, 0));
  ln_k<0><<<1568, blk, 0, stream>>>(bufA2, ldmln + 0, ldmln + 512, bufMED, nullptr, 6272);

  // ============ Phases C+D interleaved: v_af then out ============
  gemm2_k<0,128,64,2,2,2,0,0,0,0,1><<<dim3(113,8,1), blk, 0, stream>>>(
      mkP(bufMED,1,0,0,512, afW00,1,0,0,512, bufQ,1,0,0,512,
          afb + 0, nullptr, nullptr, 6272,512,512, 1.f, 0),
      mkP(xbf,1,0,0,512, afW10,1,0,0,512, bufKV,1,0,0,512,
          afb + 1024, nullptr, nullptr, 8192,512,512, 1.f, 0), 49);
  gemm2_k<0,32,256,2,1,2,1,0,0,0,2><<<dim3(15,1,32), dim3(128), 0, stream>>>(
      mkP(bufQ,1,100352L,0L,512, xbf,1,131072L,0L,512, bufS,1,50176L,0L,256,
          nullptr, nullptr, nullptr, 196,256,512, AFS, 256),
      mkP(bufKV,1,131072L,0L,512, bufMED,1,100352L,0L,512, bufSD,1,65536L,0L,256,
          nullptr, nullptr, nullptr, 256,256,512, AFS, 196), 7);
  gemm_k<0,64,128,2,2,2,0,0,0,0,2><<<dim3(4,4,32), blk, 0, stream>>>(
      mkP(bufS,1,50176L,0L,256, bufT2,1,131072L,0L,256, bufO,1,100352L,0L,512,
          nullptr, nullptr, nullptr, 196,512,256, 1.f, 0));
  gemm_k<0,128,64,2,2,2,0,0,0,1,2><<<dim3(4,4,32), blk, 0, stream>>>(
      mkP(afW01,1,0,0,512, bufO,1,100352L,0L,512, bufT,1,131072L,0L,256,
          afb + 512, nullptr, nullptr, 512,256,512, 1.f, 0));
  gemm_k<0,64,128,2,2,2,0,0,0,0,2><<<dim3(4,4,32), blk, 0, stream>>>(
      mkP(bufSD,1,65536L,0L,256, bufT,1,131072L,0L,256, bufO,1,131072L,0L,512,
          nullptr, nullptr, nullptr, 256,512,256, 1.f, 0));
  gemm_k<1,128,64,2,2,2,0,0,1,0,1><<<dim3(64,8,1), blk, 0, stream>>>(
      mkP(bufO,1,0,0,512, afW11,1,0,0,512, out,1,0,0,512,
          afb + 1536, x, nullptr, 8192,512,512, 1.f, 0));
}

// Round 19
// 328.678 us; speedup vs baseline: 1.0448x; 1.0082x over previous
//
#include <hip/hip_runtime.h>
#include <hip/hip_bf16.h>

typedef __attribute__((ext_vector_type(4))) float f32x4;
typedef __attribute__((ext_vector_type(8))) short s16x8;
typedef __attribute__((ext_vector_type(4))) short s16x4;

__device__ __forceinline__ short f2bf(float f) {
  union { float f; unsigned u; } c; c.f = f;
  unsigned r = c.u + 0x7fffu + ((c.u >> 16) & 1u);
  return (short)(r >> 16);
}
__device__ __forceinline__ float bf2f(short h) {
  union { unsigned u; float f; } c; c.u = ((unsigned)(unsigned short)h) << 16;
  return c.f;
}
__device__ __forceinline__ s16x8 cvt8(const f32x4& lo, const f32x4& hi) {
  s16x8 v;
  v[0] = f2bf(lo[0]); v[1] = f2bf(lo[1]); v[2] = f2bf(lo[2]); v[3] = f2bf(lo[3]);
  v[4] = f2bf(hi[0]); v[5] = f2bf(hi[1]); v[6] = f2bf(hi[2]); v[7] = f2bf(hi[3]);
  return v;
}

__device__ __forceinline__ void gl_lds16(const short* g, char* l) {
  __builtin_amdgcn_global_load_lds(
      (const __attribute__((address_space(1))) unsigned int*)g,
      (__attribute__((address_space(3))) unsigned int*)l, 16, 0, 0);
}

// ---------------------------------------------------------------------------
// Runtime parameter pack for one GEMM problem
// ---------------------------------------------------------------------------
struct GemmP {
  const short* A; int hbA; long sAo, sAi; int lda;
  const short* B; int hbB; long sBo, sBi; int ldb;
  void* C; int hbC; long sCo, sCi; int ldc;
  const float* bias; const float* res1; const float* res2;
  int M, N, K; float alpha; int nvalid;
};

// ---------------------------------------------------------------------------
// GEMM body (all-bf16 in): C = alpha*A[M,K]@B[N,K]^T (+bias/res/softmax)
// ---------------------------------------------------------------------------
template<int CF32, int BM, int BN, int WRN, int WCN, int RING,
         int SM, int RELU, int NRES, int BIASM>
__device__ __forceinline__
void gemm_body(const GemmP& P, int bx, int by, int bz)
{
  constexpr int WAVES = WRN * WCN;
  constexpr int T = WAVES * 64;
  constexpr int MI = BM / (WRN * 16), NI = BN / (WCN * 16);
  constexpr int ACH = BM * 8 / T, BCH = BN * 8 / T;
  constexpr int L   = ACH + BCH;
  constexpr int ABYTES = BM * 128;
  constexpr int TBYTES = (BM + BN) * 128;
  constexpr int LSTR = BN + (CF32 ? 4 : 8);
  constexpr int EPIB = BM * LSTR * (CF32 ? 4 : 2);
  constexpr int SMEMB = (RING * TBYTES > EPIB) ? RING * TBYTES : EPIB;
  __shared__ __align__(16) char smem[SMEMB];

  const int tid  = threadIdx.x;
  const int lane = tid & 63;
  const int wid  = tid >> 6;
  const int wr   = wid / WCN, wc = wid % WCN;

  const int m0 = bx * BM, n0 = by * BN;
  const int z  = bz;

  const int zA = z / P.hbA, zAi = z - zA * P.hbA;
  const int zB = z / P.hbB, zBi = z - zB * P.hbB;
  const int zC = z / P.hbC, zCi = z - zC * P.hbC;
  const short* Ab = P.A + (long)zA * P.sAo + (long)zAi * P.sAi;
  const short* Bb = P.B + (long)zB * P.sBo + (long)zBi * P.sBi;
  char*        Cb = (char*)P.C + ((long)zC * P.sCo + (long)zCi * P.sCi) * (CF32 ? 4 : 2);

  int aL[ACH]; long aG[ACH];
#pragma unroll
  for (int j = 0; j < ACH; ++j) {
    int chunk = (j * WAVES + wid) * 64 + lane;
    int row = chunk >> 3;
    int c   = (chunk & 7) ^ (row & 7);
    int gr = m0 + row; if (gr > P.M - 1) gr = P.M - 1;
    aL[j] = chunk * 16;
    aG[j] = (long)gr * P.lda + c * 8;
  }
  int bL[BCH]; long bG[BCH];
#pragma unroll
  for (int j = 0; j < BCH; ++j) {
    int chunk = (j * WAVES + wid) * 64 + lane;
    int row = chunk >> 3;
    int c   = (chunk & 7) ^ (row & 7);
    int gc = n0 + row; if (gc > P.N - 1) gc = P.N - 1;
    bL[j] = chunk * 16;
    bG[j] = (long)gc * P.ldb + c * 8;
  }

  auto stage = [&](int buf, int kt) {
    const short* Akt = Ab + (long)kt * 64;
    char* base = smem + buf * TBYTES;
#pragma unroll
    for (int j = 0; j < ACH; ++j) gl_lds16(Akt + aG[j], base + aL[j]);
    const short* Bkt = Bb + (long)kt * 64;
#pragma unroll
    for (int j = 0; j < BCH; ++j) gl_lds16(Bkt + bG[j], base + ABYTES + bL[j]);
  };

  int ard[2][MI], brd[2][NI];
#pragma unroll
  for (int kk = 0; kk < 2; ++kk) {
    int kgr = kk * 4 + (lane >> 4);
#pragma unroll
    for (int mi = 0; mi < MI; ++mi) {
      int m = wr * (BM / WRN) + mi * 16 + (lane & 15);
      ard[kk][mi] = m * 128 + ((kgr ^ (m & 7)) << 4);
    }
#pragma unroll
    for (int ni = 0; ni < NI; ++ni) {
      int n = wc * (BN / WCN) + ni * 16 + (lane & 15);
      brd[kk][ni] = ABYTES + n * 128 + ((kgr ^ (n & 7)) << 4);
    }
  }

  const int NT = P.K >> 6;
#pragma unroll
  for (int p = 0; p < RING; ++p) if (p < NT) stage(p, p);

  f32x4 acc[MI][NI];
#pragma unroll
  for (int mi = 0; mi < MI; ++mi)
#pragma unroll
    for (int ni = 0; ni < NI; ++ni) acc[mi][ni] = (f32x4){0.f, 0.f, 0.f, 0.f};

  int bufi = 0;
  for (int t = 0; t < NT; ++t) {
    const int rem = NT - t;
    if constexpr (RING == 3) {
      if (rem >= 3)      asm volatile("s_waitcnt vmcnt(%0)" :: "n"(2 * L) : "memory");
      else if (rem == 2) asm volatile("s_waitcnt vmcnt(%0)" :: "n"(L) : "memory");
      else               asm volatile("s_waitcnt vmcnt(0)" ::: "memory");
    } else if constexpr (RING == 2) {
      if (rem >= 2)      asm volatile("s_waitcnt vmcnt(%0)" :: "n"(L) : "memory");
      else               asm volatile("s_waitcnt vmcnt(0)" ::: "memory");
    } else {
      asm volatile("s_waitcnt vmcnt(0)" ::: "memory");
    }
    asm volatile("s_barrier" ::: "memory");

    const char* base = smem + bufi * TBYTES;
#pragma unroll
    for (int kk = 0; kk < 2; ++kk) {
      s16x8 af[MI];
#pragma unroll
      for (int mi = 0; mi < MI; ++mi) af[mi] = *(const s16x8*)(base + ard[kk][mi]);
#pragma unroll
      for (int ni = 0; ni < NI; ++ni) {
        s16x8 bf = *(const s16x8*)(base + brd[kk][ni]);
#pragma unroll
        for (int mi = 0; mi < MI; ++mi)
          acc[mi][ni] = __builtin_amdgcn_mfma_f32_16x16x32_bf16(af[mi], bf, acc[mi][ni], 0, 0, 0);
      }
    }

    if (t + RING < NT) {
      asm volatile("s_waitcnt lgkmcnt(0)" ::: "memory");
      asm volatile("s_barrier" ::: "memory");
      stage(bufi, t + RING);
    }
    bufi = (bufi + 1 == RING) ? 0 : bufi + 1;
  }

  if constexpr (SM) {
#pragma unroll
    for (int mi = 0; mi < MI; ++mi) {
#pragma unroll
      for (int j = 0; j < 4; ++j) {
        float mx = -3.0e38f;
#pragma unroll
        for (int ni = 0; ni < NI; ++ni) {
          int col = n0 + wc * (BN / WCN) + ni * 16 + (lane & 15);
          float s = acc[mi][ni][j] * P.alpha;
          acc[mi][ni][j] = (col < P.nvalid) ? s : -3.0e38f;
          mx = fmaxf(mx, acc[mi][ni][j]);
        }
#pragma unroll
        for (int o = 1; o < 16; o <<= 1) mx = fmaxf(mx, __shfl_xor(mx, o));
        float sum = 0.f;
#pragma unroll
        for (int ni = 0; ni < NI; ++ni) {
          int col = n0 + wc * (BN / WCN) + ni * 16 + (lane & 15);
          float e = (col < P.nvalid) ? __expf(acc[mi][ni][j] - mx) : 0.f;
          acc[mi][ni][j] = e;
          sum += e;
        }
#pragma unroll
        for (int o = 1; o < 16; o <<= 1) sum += __shfl_xor(sum, o);
        float inv = 1.f / sum;
#pragma unroll
        for (int ni = 0; ni < NI; ++ni) acc[mi][ni][j] *= inv;
      }
    }
  }
  const float aep = SM ? 1.f : P.alpha;

  asm volatile("s_waitcnt lgkmcnt(0)" ::: "memory");
  __syncthreads();

  {
    float* lf = (float*)smem;
    short* lh = (short*)smem;
#pragma unroll
    for (int mi = 0; mi < MI; ++mi)
#pragma unroll
      for (int ni = 0; ni < NI; ++ni) {
        int c_loc = wc * (BN / WCN) + ni * 16 + (lane & 15);
        float bv = (P.bias && !BIASM) ? P.bias[n0 + c_loc] : 0.f;
        int rb = wr * (BM / WRN) + mi * 16 + ((lane >> 4) << 2);
#pragma unroll
        for (int j = 0; j < 4; ++j) {
          float v = acc[mi][ni][j] * aep + bv;
          if constexpr (CF32) lf[(rb + j) * LSTR + c_loc] = v;
          else                lh[(rb + j) * LSTR + c_loc] = f2bf(v);
        }
      }
  }
  __syncthreads();

  constexpr int CPR = BN / 8;
  constexpr int RP  = T / CPR;
  const int rr0 = tid / CPR;
  const int cc  = (tid % CPR) * 8;
  for (int r = rr0; r < BM; r += RP) {
    const int gr = m0 + r;
    if (gr >= P.M) break;
    f32x4 a, b;
    if constexpr (CF32) {
      a = *(const f32x4*)((const float*)smem + (long)r * LSTR + cc);
      b = *(const f32x4*)((const float*)smem + (long)r * LSTR + cc + 4);
    } else {
      s16x8 h = *(const s16x8*)((const short*)smem + (long)r * LSTR + cc);
#pragma unroll
      for (int j = 0; j < 4; ++j) { a[j] = bf2f(h[j]); b[j] = bf2f(h[j + 4]); }
    }
    if constexpr (BIASM) {
      float bm = P.bias[gr];
#pragma unroll
      for (int j = 0; j < 4; ++j) { a[j] += bm; b[j] += bm; }
    }
    const long gb = (long)gr * P.ldc + n0 + cc;
    if constexpr (NRES >= 1) {
      f32x4 r1 = *(const f32x4*)(P.res1 + gb), r2 = *(const f32x4*)(P.res1 + gb + 4);
#pragma unroll
      for (int j = 0; j < 4; ++j) { a[j] += r1[j]; b[j] += r2[j]; }
    }
    if constexpr (NRES >= 2) {
      f32x4 r1 = *(const f32x4*)(P.res2 + gb), r2 = *(const f32x4*)(P.res2 + gb + 4);
#pragma unroll
      for (int j = 0; j < 4; ++j) { a[j] += r1[j]; b[j] += r2[j]; }
    }
    if constexpr (RELU) {
#pragma unroll
      for (int j = 0; j < 4; ++j) { a[j] = fmaxf(a[j], 0.f); b[j] = fmaxf(b[j], 0.f); }
    }
    if constexpr (CF32) {
      *(f32x4*)((float*)Cb + gb) = a;
      *(f32x4*)((float*)Cb + gb + 4) = b;
    } else {
      *(s16x8*)((short*)Cb + gb) = cvt8(a, b);
    }
  }
}

// XCD-chunked bijective remap over a linear id
__device__ __forceinline__ int xcd_remap(int o, int nwg)
{
  const int q = nwg >> 3, r = nwg & 7;
  const int xcd = o & 7, slot = o >> 3;
  return (xcd < r ? xcd * (q + 1) : r * (q + 1) + (xcd - r) * q) + slot;
}

// ---------------------------------------------------------------------------
// Single-problem GEMM kernel
// ---------------------------------------------------------------------------
template<int CF32, int BM, int BN, int WRN, int WCN, int RING,
         int SM, int RELU, int NRES, int BIASM, int SWZ>
__global__ __launch_bounds__(WRN * WCN * 64, 2)
void gemm_k(GemmP P)
{
  int bx = blockIdx.x, by = blockIdx.y, bz = blockIdx.z;
  if constexpr (SWZ == 1) {
    const int gx = gridDim.x, gy = gridDim.y;
    const int w = xcd_remap(by * gx + bx, gx * gy);
    bx = w / gy; by = w - bx * gy;
  } else if constexpr (SWZ == 2) {
    const int gx = gridDim.x, gy = gridDim.y, gz = gridDim.z;
    int w = xcd_remap((bz * gy + by) * gx + bx, gx * gy * gz);
    bx = w % gx; w /= gx; by = w % gy; bz = w / gy;
  }
  gemm_body<CF32, BM, BN, WRN, WCN, RING, SM, RELU, NRES, BIASM>(P, bx, by, bz);
}

// ---------------------------------------------------------------------------
// Dual-problem GEMM kernel: blocks with remapped bx < split run p0, else p1.
// ---------------------------------------------------------------------------
template<int CF32, int BM, int BN, int WRN, int WCN, int RING,
         int SM, int RELU, int NRES, int BIASM, int SWZ>
__global__ __launch_bounds__(WRN * WCN * 64, 2)
void gemm2_k(GemmP p0, GemmP p1, int split)
{
  int bx = blockIdx.x, by = blockIdx.y, bz = blockIdx.z;
  if constexpr (SWZ == 1) {
    const int gx = gridDim.x, gy = gridDim.y;
    const int w = xcd_remap(by * gx + bx, gx * gy);
    bx = w / gy; by = w - bx * gy;
  } else if constexpr (SWZ == 2) {
    const int gx = gridDim.x, gy = gridDim.y, gz = gridDim.z;
    int w = xcd_remap((bz * gy + by) * gx + bx, gx * gy * gz);
    bx = w % gx; w /= gx; by = w % gy; bz = w / gy;
  }
  const bool first = (bx < split);
  const GemmP& P = first ? p0 : p1;
  if (!first) bx -= split;
  gemm_body<CF32, BM, BN, WRN, WCN, RING, SM, RELU, NRES, BIASM>(P, bx, by, bz);
}

// ---------------------------------------------------------------------------
// Fused MHA with XCD-chunked block remap
// ---------------------------------------------------------------------------
__global__ __launch_bounds__(256, 2)
void mha_k(const short* __restrict__ Qp, long qStride,
           const short* __restrict__ Kp, long kStride, int ldk, int Lkv,
           const short* __restrict__ VTp, long vtStride,
           short* __restrict__ Op, int Lq, float alpha, int nvalid)
{
  __shared__ __align__(16) char smem[73728];
  char* Qs  = smem;
  char* Ks  = smem + 8192;
  char* VTs = smem + 40960;

  const int tid = threadIdx.x, lane = tid & 63, wid = tid >> 6;

  int bxr = blockIdx.x, bzr = blockIdx.z;
  {
    const int gx = gridDim.x, gz = gridDim.z;
    int w = xcd_remap(bzr * gx + bxr, gx * gz);
    bxr = w % gx; bzr = w / gx;
  }
  const int z = bzr, b = z >> 3, h = z & 7;
  const int m0 = bxr * 64;

  const short* Qb  = Qp + (long)b * qStride + h * 64;
  const short* Kb  = Kp + (long)b * kStride + h * 64;
  const short* VTb = VTp + (long)z * vtStride;
  short*       Ob  = Op + (long)b * qStride + h * 64;

#pragma unroll
  for (int j = 0; j < 2; ++j) {
    int chunk = (j * 4 + wid) * 64 + lane;
    int row = chunk >> 3, c = (chunk & 7) ^ (row & 7);
    int gr = m0 + row; if (gr > Lq - 1) gr = Lq - 1;
    gl_lds16(Qb + (long)gr * 512 + c * 8, Qs + chunk * 16);
  }
#pragma unroll
  for (int j = 0; j < 8; ++j) {
    int chunk = (j * 4 + wid) * 64 + lane;
    int row = chunk >> 3, c = (chunk & 7) ^ (row & 7);
    int gr = row; if (gr > Lkv - 1) gr = Lkv - 1;
    gl_lds16(Kb + (long)gr * ldk + c * 8, Ks + chunk * 16);
  }
#pragma unroll
  for (int j = 0; j < 8; ++j) {
    int chunk = (j * 4 + wid) * 64 + lane;
    int row = chunk >> 5, cw = (chunk & 31) ^ (row & 15);
    gl_lds16(VTb + (long)row * 256 + cw * 8, VTs + chunk * 16);
  }
  __syncthreads();

  f32x4 acc[16];
#pragma unroll
  for (int ni = 0; ni < 16; ++ni) acc[ni] = (f32x4){0.f, 0.f, 0.f, 0.f};
#pragma unroll
  for (int kk = 0; kk < 2; ++kk) {
    int kgr = kk * 4 + (lane >> 4);
    int m = wid * 16 + (lane & 15);
    s16x8 af = *(const s16x8*)(Qs + m * 128 + ((kgr ^ (m & 7)) << 4));
#pragma unroll
    for (int ni = 0; ni < 16; ++ni) {
      int n = ni * 16 + (lane & 15);
      s16x8 bf = *(const s16x8*)(Ks + n * 128 + ((kgr ^ (n & 7)) << 4));
      acc[ni] = __builtin_amdgcn_mfma_f32_16x16x32_bf16(af, bf, acc[ni], 0, 0, 0);
    }
  }

#pragma unroll
  for (int j = 0; j < 4; ++j) {
    float mx = -3.0e38f;
#pragma unroll
    for (int ni = 0; ni < 16; ++ni) {
      int col = ni * 16 + (lane & 15);
      float s = acc[ni][j] * alpha;
      acc[ni][j] = (col < nvalid) ? s : -3.0e38f;
      mx = fmaxf(mx, acc[ni][j]);
    }
#pragma unroll
    for (int o = 1; o < 16; o <<= 1) mx = fmaxf(mx, __shfl_xor(mx, o));
    float sum = 0.f;
#pragma unroll
    for (int ni = 0; ni < 16; ++ni) {
      int col = ni * 16 + (lane & 15);
      float e = (col < nvalid) ? __expf(acc[ni][j] - mx) : 0.f;
      acc[ni][j] = e;
      sum += e;
    }
#pragma unroll
    for (int o = 1; o < 16; o <<= 1) sum += __shfl_xor(sum, o);
    float inv = 1.f / sum;
#pragma unroll
    for (int ni = 0; ni < 16; ++ni) acc[ni][j] *= inv;
  }

  __syncthreads();

  {
    char* Ps = Ks + wid * 8192;
    const int r0 = (lane >> 4) * 4;
#pragma unroll
    for (int ni = 0; ni < 16; ++ni) {
      int col = ni * 16 + (lane & 15);
      int chunk = col >> 3, cin = (col & 7) * 2;
#pragma unroll
      for (int j = 0; j < 4; ++j) {
        int row = r0 + j;
        *(short*)(Ps + row * 512 + ((chunk ^ (row & 15)) << 4) + cin) = f2bf(acc[ni][j]);
      }
    }
  }
  asm volatile("s_waitcnt lgkmcnt(0)" ::: "memory");

  f32x4 acco[4];
#pragma unroll
  for (int ni = 0; ni < 4; ++ni) acco[ni] = (f32x4){0.f, 0.f, 0.f, 0.f};
  {
    const char* Ps = Ks + wid * 8192;
#pragma unroll
    for (int kk = 0; kk < 8; ++kk) {
      int g = lane >> 4;
      int mrow = lane & 15;
      int achunk = (kk * 4 + g) ^ (mrow & 15);
      s16x8 af = *(const s16x8*)(Ps + mrow * 512 + (achunk << 4));
#pragma unroll
      for (int ni = 0; ni < 4; ++ni) {
        int n = ni * 16 + (lane & 15);
        int bchunk = (kk * 4 + g) ^ (n & 15);
        s16x8 bf = *(const s16x8*)(VTs + n * 512 + (bchunk << 4));
        acco[ni] = __builtin_amdgcn_mfma_f32_16x16x32_bf16(af, bf, acco[ni], 0, 0, 0);
      }
    }
  }

  __syncthreads();

  {
    short* lh = (short*)smem;
#pragma unroll
    for (int ni = 0; ni < 4; ++ni) {
      int d = ni * 16 + (lane & 15);
      int rb = wid * 16 + ((lane >> 4) << 2);
#pragma unroll
      for (int j = 0; j < 4; ++j) lh[(rb + j) * 72 + d] = f2bf(acco[ni][j]);
    }
  }
  __syncthreads();
  {
    const int r0 = tid >> 3, cc = (tid & 7) * 8;
#pragma unroll
    for (int p = 0; p < 2; ++p) {
      int r = r0 + p * 32;
      int gr = m0 + r;
      if (gr < Lq) {
        s16x8 h8 = *(const s16x8*)((const short*)smem + r * 72 + cc);
        *(s16x8*)(Ob + (long)gr * 512 + cc) = h8;
      }
    }
  }
}

// ---------------------------------------------------------------------------
// Merged prep: weight transposes (z<16), x/text fp32->bf16 (z 16-31),
// x^T per-batch transpose (z 32-63). One dispatch.
// ---------------------------------------------------------------------------
__global__ __launch_bounds__(256)
void prep_k(const float* ftw, const float* fvw, const float* afw,
            const float* ftw1, const float* fvw1,
            const float* ftw2, const float* fvw2,
            const float* x, const float* text,
            short* wTbase, short* dW1, short* dW2,
            short* xbf, short* textbf, short* xT)
{
  const int z = blockIdx.y, zt = blockIdx.x;

  if (z >= 16 && z < 32) {
    long off = (long)(z & 7) * 524288 + (long)zt * 2048 + threadIdx.x * 8;
    const float* src = (z < 24 ? x : text) + off;
    short* dst = (z < 24 ? xbf : textbf) + off;
    f32x4 lo = *(const f32x4*)src, hi = *(const f32x4*)(src + 4);
    *(s16x8*)dst = cvt8(lo, hi);
    return;
  }

  __shared__ float tile[64][65];
  const float* in; short* out;
  int R_in, rs_in, Rpad, tiles_r;
  if (z < 12) {
    if (zt >= 64) return;
    const int grp = z >> 2, idx = z & 3;
    in = (grp == 0 ? ftw : grp == 1 ? fvw : afw) + (long)idx * 262144;
    out = wTbase + (long)grp * 3145728 + (long)idx * 262144;
    R_in = 512; rs_in = 512; Rpad = 512; tiles_r = 8;
  } else if (z < 14) {
    const int idx = z - 12;
    in = (idx == 0 ? ftw1 : fvw1);
    out = (idx == 0 ? dW1 : dW1 + 3145728);
    R_in = 512; rs_in = 2048; Rpad = 512; tiles_r = 8;
  } else if (z < 16) {
    const int idx = z - 14;
    in = (idx == 0 ? ftw2 : fvw2);
    out = (idx == 0 ? dW2 : dW2 + 3145728);
    R_in = 2048; rs_in = 512; Rpad = 2048; tiles_r = 32;
  } else {
    if (zt >= 32) return;
    const int b = z - 32;
    in = x + (long)b * 131072;
    out = xT + (long)b * 131072;
    R_in = 256; rs_in = 512; Rpad = 256; tiles_r = 4;
  }
  const int tr = zt % tiles_r, tc = zt / tiles_r;
  const int r0 = tr * 64, c0 = tc * 64;
  const int c = threadIdx.x & 63, l0 = threadIdx.x >> 6;

#pragma unroll 4
  for (int i = 0; i < 16; ++i) {
    int l = l0 + i * 4;
    int gr = r0 + l;
    float v = 0.f;
    if (gr < R_in) v = in[(long)gr * rs_in + c0 + c];
    tile[l][c] = v;
  }
  __syncthreads();
#pragma unroll 4
  for (int i = 0; i < 16; ++i) {
    int cr = l0 + i * 4;
    out[(long)(c0 + cr) * Rpad + r0 + c] = f2bf(tile[c][cr]);
  }
}

// ---------------------------------------------------------------------------
template<int RAW>
__global__ __launch_bounds__(256)
void ln_k(const float* __restrict__ in, const float* __restrict__ g,
          const float* __restrict__ b, short* __restrict__ outp,
          short* __restrict__ rawp, int rows)
{
  int row = blockIdx.x * 4 + (threadIdx.x >> 6);
  if (row >= rows) return;
  int lane = threadIdx.x & 63;
  const float* p = in + (long)row * 512 + lane * 8;
  f32x4 v0 = *(const f32x4*)p, v1 = *(const f32x4*)(p + 4);
  if constexpr (RAW) {
    short* rp = rawp + (long)row * 512 + lane * 8;
    *(s16x8*)rp = cvt8(v0, v1);
  }
  float s = 0.f, sq = 0.f;
#pragma unroll
  for (int j = 0; j < 4; ++j) { s += v0[j] + v1[j]; sq += v0[j]*v0[j] + v1[j]*v1[j]; }
#pragma unroll
  for (int o = 1; o < 64; o <<= 1) { s += __shfl_xor(s, o); sq += __shfl_xor(sq, o); }
  float mean = s * (1.f / 512.f);
  float var  = sq * (1.f / 512.f) - mean * mean;
  float rs   = rsqrtf(var + 1e-6f);
  const f32x4 g0 = *(const f32x4*)(g + lane * 8), g1 = *(const f32x4*)(g + lane * 8 + 4);
  const f32x4 b0 = *(const f32x4*)(b + lane * 8), b1 = *(const f32x4*)(b + lane * 8 + 4);
  f32x4 o0, o1;
#pragma unroll
  for (int j = 0; j < 4; ++j) {
    o0[j] = g0[j] * (v0[j] - mean) * rs + b0[j];
    o1[j] = g1[j] * (v1[j] - mean) * rs + b1[j];
  }
  short* op = outp + (long)row * 512 + lane * 8;
  *(s16x8*)op = cvt8(o0, o1);
}

// ---------------------------------------------------------------------------
static GemmP mkP(const short* A, int hbA, long sAo, long sAi, int lda,
                 const short* B, int hbB, long sBo, long sBi, int ldb,
                 void* C, int hbC, long sCo, long sCi, int ldc,
                 const float* bias, const float* r1, const float* r2,
                 int M, int N, int K, float alpha, int nvalid)
{
  GemmP P;
  P.A = A; P.hbA = hbA; P.sAo = sAo; P.sAi = sAi; P.lda = lda;
  P.B = B; P.hbB = hbB; P.sBo = sBo; P.sBi = sBi; P.ldb = ldb;
  P.C = C; P.hbC = hbC; P.sCo = sCo; P.sCi = sCi; P.ldc = ldc;
  P.bias = bias; P.res1 = r1; P.res2 = r2;
  P.M = M; P.N = N; P.K = K; P.alpha = alpha; P.nvalid = nvalid;
  return P;
}

extern "C" void kernel_launch(void* const* d_in, const int* in_sizes, int n_in,
                              void* d_out, int out_size, void* d_ws, size_t ws_size,
                              hipStream_t stream)
{
  (void)in_sizes; (void)n_in; (void)out_size; (void)ws_size;

  const float* x     = (const float*)d_in[0];
  const float* text  = (const float*)d_in[1];
  const float* vis   = (const float*)d_in[2];
  const float* ftw   = (const float*)d_in[3];
  const float* ftb   = (const float*)d_in[4];
  const float* ftw1  = (const float*)d_in[5];
  const float* ftb1  = (const float*)d_in[6];
  const float* ftw2  = (const float*)d_in[7];
  const float* ftb2  = (const float*)d_in[8];
  const float* ftln  = (const float*)d_in[9];
  const float* fvw   = (const float*)d_in[10];
  const float* fvb   = (const float*)d_in[11];
  const float* fvw1  = (const float*)d_in[12];
  const float* fvb1  = (const float*)d_in[13];
  const float* fvw2  = (const float*)d_in[14];
  const float* fvb2  = (const float*)d_in[15];
  const float* fvln  = (const float*)d_in[16];
  const float* ldmln = (const float*)d_in[17];
  const float* afw   = (const float*)d_in[18];
  const float* afb   = (const float*)d_in[19];
  float* out = (float*)d_out;

  char* ws = (char*)d_ws;
  short* wT     = (short*)ws;
  short* xbf    = (short*)(ws + 14680064);
  short* bufLN  = (short*)(ws + 23068672);
  short* bufQ   = (short*)(ws + 29491200);
  short* bufKV  = (short*)(ws + 37879808);
  short* bufT   = (short*)(ws + 54657024);
  short* bufS   = (short*)(ws + 63045632);
  short* bufO   = (short*)(ws + 88735744);
  float* bufX1  = (float*)(ws + 97124352);
  float* bufA2  = (float*)(ws + 109969408);
  short* bufMED = (short*)(ws + 122814464);
  short* bufT2  = (short*)(ws + 129236992);   // x^T, 8,388,608 B
  short* textbf = bufO;
  short* visbf  = (short*)bufA2;
  short* bufSD  = bufS + 2097152;             // D-scores region

  short* ftWq  = wT + 0;
  short* ftWk  = wT + 262144;
  short* ftWv  = wT + 524288;
  short* ftWo  = wT + 786432;
  short* ftW1t = wT + 1048576;
  short* ftW2t = wT + 2097152;
  short* fvWq  = wT + 3145728;
  short* fvWk  = wT + 3407872;
  short* fvWv  = wT + 3670016;
  short* fvWo  = wT + 3932160;
  short* fvW1t = wT + 4194304;
  short* fvW2t = wT + 5242880;
  short* afW00 = wT + 6291456;
  short* afW01 = wT + 6553600;
  short* afW10 = wT + 6815744;
  short* afW11 = wT + 7077888;

  const float AFS = 0.04419417382415922f;
  dim3 blk(256);

  // ---- prep: single merged dispatch (weights + converts + x^T) ----
  prep_k<<<dim3(256, 64), blk, 0, stream>>>(
      ftw, fvw, afw, ftw1, fvw1, ftw2, fvw2, x, text,
      wT, ftW1t, ftW2t, xbf, textbf, bufT2);

  // ================= Phase A: cross_layer(vis, text, ft) =================
  ln_k<1><<<1568, blk, 0, stream>>>(vis, ftln + 0, ftln + 512, bufLN, visbf, 6272);
  // merged Q-proj + K-proj  (RING=2: 48KB LDS -> 3 blocks/CU)
  gemm2_k<0,128,64,2,2,2,0,0,0,0,1><<<dim3(113,8,1), blk, 0, stream>>>(
      mkP(bufLN,1,0,0,512, ftWq,1,0,0,512, bufQ,1,0,0,512,
          ftb + 0, nullptr, nullptr, 6272,512,512, 1.f, 0),
      mkP(textbf,1,0,0,512, ftWk,1,0,0,512, bufKV,1,0,0,512,
          ftb + 512, nullptr, nullptr, 8192,512,512, 1.f, 0), 49);
  gemm_k<0,128,64,2,2,2,0,0,0,1,2><<<dim3(4,4,32), blk, 0, stream>>>(
      mkP(ftWv,1,0,0,512, textbf,1,131072L,0L,512, bufT,1,131072L,0L,256,
          ftb + 1024, nullptr, nullptr, 512,256,512, 1.f, 0));
  mha_k<<<dim3(4,1,256), blk, 0, stream>>>(bufQ, 100352L, bufKV, 131072L, 512, 256,
      bufT, 16384L, bufO, 196, 0.125f, 256);
  gemm_k<1,128,64,2,2,2,0,0,1,0,1><<<dim3(49,8,1), blk, 0, stream>>>(
      mkP(bufO,1,0,0,512, ftWo,1,0,0,512, bufX1,1,0,0,512,
          ftb + 1536, vis, nullptr, 6272,512,512, 1.f, 0));
  ln_k<0><<<1568, blk, 0, stream>>>(bufX1, ftln + 1024, ftln + 1536, bufLN, nullptr, 6272);
  // FFN1: 128x64 tile, RING=2 -> 48KB LDS, 3 blocks/CU, grid 1568
  gemm_k<0,128,64,2,2,2,0,1,0,0,1><<<dim3(49,32,1), blk, 0, stream>>>(
      mkP(bufLN,1,0,0,512, ftW1t,1,0,0,512, bufS,1,0,0,2048,
          ftb1, nullptr, nullptr, 6272,2048,512, 1.f, 0));
  gemm_k<1,128,64,2,2,2,0,0,1,0,1><<<dim3(49,8,1), blk, 0, stream>>>(
      mkP(bufS,1,0,0,2048, ftW2t,1,0,0,2048, bufX1,1,0,0,512,
          ftb2, bufX1, nullptr, 6272,512,2048, 1.f, 0));

  // ================= Phase B: cross_layer(med1, vis, fv) + med1 =================
  ln_k<0><<<1568, blk, 0, stream>>>(bufX1, fvln + 0, fvln + 512, bufLN, nullptr, 6272);
  gemm2_k<0,128,64,2,2,2,0,0,0,0,1><<<dim3(98,8,1), blk, 0, stream>>>(
      mkP(bufLN,1,0,0,512, fvWq,1,0,0,512, bufQ,1,0,0,512,
          fvb + 0, nullptr, nullptr, 6272,512,512, 1.f, 0),
      mkP(visbf,1,0,0,512, fvWk,1,0,0,512, bufKV,1,0,0,512,
          fvb + 512, nullptr, nullptr, 6272,512,512, 1.f, 0), 49);
  gemm_k<0,128,64,2,2,2,0,0,0,1,2><<<dim3(4,4,32), blk, 0, stream>>>(
      mkP(fvWv,1,0,0,512, visbf,1,100352L,0L,512, bufT,1,131072L,0L,256,
          fvb + 1024, nullptr, nullptr, 512,196,512, 1.f, 0));
  mha_k<<<dim3(4,1,256), blk, 0, stream>>>(bufQ, 100352L, bufKV, 100352L, 512, 196,
      bufT, 16384L, bufO, 196, 0.125f, 196);
  gemm_k<1,128,64,2,2,2,0,0,1,0,1><<<dim3(49,8,1), blk, 0, stream>>>(
      mkP(bufO,1,0,0,512, fvWo,1,0,0,512, bufA2,1,0,0,512,
          fvb + 1536, bufX1, nullptr, 6272,512,512, 1.f, 0));
  ln_k<0><<<1568, blk, 0, stream>>>(bufA2, fvln + 1024, fvln + 1536, bufLN, nullptr, 6272);
  // FFN1: 128x64 tile, RING=2 -> 3 blocks/CU
  gemm_k<0,128,64,2,2,2,0,1,0,0,1><<<dim3(49,32,1), blk, 0, stream>>>(
      mkP(bufLN,1,0,0,512, fvW1t,1,0,0,512, bufS,1,0,0,2048,
          fvb1, nullptr, nullptr, 6272,2048,512, 1.f, 0));
  gemm_k<1,128,64,2,2,2,0,0,2,0,1><<<dim3(49,8,1), blk, 0, stream>>>(
      mkP(bufS,1,0,0,2048, fvW2t,1,0,0,2048, bufA2,1,0,0,512,
          fvb2, bufA2, bufX1, 6272,512,2048, 1.f, 0));
  ln_k<0><<<1568, blk, 0, stream>>>(bufA2, ldmln + 0, ldmln + 512, bufMED, nullptr, 6272);

  // ============ Phases C+D interleaved: v_af then out ============
  gemm2_k<0,128,64,2,2,2,0,0,0,0,1><<<dim3(113,8,1), blk, 0, stream>>>(
      mkP(bufMED,1,0,0,512, afW00,1,0,0,512, bufQ,1,0,0,512,
          afb + 0, nullptr, nullptr, 6272,512,512, 1.f, 0),
      mkP(xbf,1,0,0,512, afW10,1,0,0,512, bufKV,1,0,0,512,
          afb + 1024, nullptr, nullptr, 8192,512,512, 1.f, 0), 49);
  gemm2_k<0,32,256,2,1,2,1,0,0,0,2><<<dim3(15,1,32), dim3(128), 0, stream>>>(
      mkP(bufQ,1,100352L,0L,512, xbf,1,131072L,0L,512, bufS,1,50176L,0L,256,
          nullptr, nullptr, nullptr, 196,256,512, AFS, 256),
      mkP(bufKV,1,131072L,0L,512, bufMED,1,100352L,0L,512, bufSD,1,65536L,0L,256,
          nullptr, nullptr, nullptr, 256,256,512, AFS, 196), 7);
  gemm_k<0,64,128,2,2,2,0,0,0,0,2><<<dim3(4,4,32), blk, 0, stream>>>(
      mkP(bufS,1,50176L,0L,256, bufT2,1,131072L,0L,256, bufO,1,100352L,0L,512,
          nullptr, nullptr, nullptr, 196,512,256, 1.f, 0));
  gemm_k<0,128,64,2,2,2,0,0,0,1,2><<<dim3(4,4,32), blk, 0, stream>>>(
      mkP(afW01,1,0,0,512, bufO,1,100352L,0L,512, bufT,1,131072L,0L,256,
          afb + 512, nullptr, nullptr, 512,256,512, 1.f, 0));
  gemm_k<0,64,128,2,2,2,0,0,0,0,2><<<dim3(4,4,32), blk, 0, stream>>>(
      mkP(bufSD,1,65536L,0L,256, bufT,1,131072L,0L,256, bufO,1,131072L,0L,512,
          nullptr, nullptr, nullptr, 256,512,256, 1.f, 0));
  gemm_k<1,128,64,2,2,2,0,0,1,0,1><<<dim3(64,8,1), blk, 0, stream>>>(
      mkP(bufO,1,0,0,512, afW11,1,0,0,512, out,1,0,0,512,
          afb + 1536, x, nullptr, 8192,512,512, 1.f, 0));
}